// Round 9
// baseline (739.202 us; speedup 1.0000x reference)
//
#include <hip/hip_runtime.h>
#include <hip/hip_bf16.h>
#include <math.h>

#define N_NODES   100000
#define N_EDGES   1600000
#define IN_FEAT   50
#define HIDDEN    64
#define N_CLASSES 41
#define NC48      48          // padded class width
#define N_TILES   (N_NODES / 16)   // 6250 exactly

#define BUCK_SHIFT 7
#define N_BUCK     ((N_NODES + 127) >> 7)    // 782

#define SCAN_CHUNK 2048
#define SCAN_NBLK  ((N_NODES + SCAN_CHUNK - 1) / SCAN_CHUNK)   // 49 (<=64)

typedef __attribute__((ext_vector_type(8))) _Float16 half8;
typedef __attribute__((ext_vector_type(4))) float   float4v;

// ---------------------------------------------------------------------------
// Zero the per-node counters (replaces hipMemsetAsync / fillBufferAligned).
// ---------------------------------------------------------------------------
__global__ __launch_bounds__(256) void zeroc_kernel(int* __restrict__ counts) {
  int i = blockIdx.x * 256 + threadIdx.x;
  if (i < N_NODES) counts[i] = 0;
}

// ---------------------------------------------------------------------------
// Prep A: x (f32 [N][50]) -> xh (f16 [N][64], k-padded with zeros)
// ---------------------------------------------------------------------------
__global__ __launch_bounds__(256) void packx_kernel(
    const float* __restrict__ x, _Float16* __restrict__ xh) {
  int i = blockIdx.x * 256 + threadIdx.x;
  if (i >= N_NODES * 64) return;
  int node = i >> 6, c = i & 63;
  xh[i] = (c < IN_FEAT) ? (_Float16)x[node * IN_FEAT + c] : (_Float16)0.f;
}

// ---------------------------------------------------------------------------
// Prep B: pack transposed f16-pair weights for MFMA B-fragments.
//   wt1l/wt1r: [64 n][32 kp]  from W1l/W1r [50][64]  (k>=50 zero)
//   wt2l/wt2r: [48 n][32 kp]  from W2l/W2r [64][41]  (n>=41 zero)
// ---------------------------------------------------------------------------
__global__ __launch_bounds__(256) void packwts_kernel(
    const float* __restrict__ W1l, const float* __restrict__ W1r,
    const float* __restrict__ W2l, const float* __restrict__ W2r,
    unsigned* __restrict__ wt1l, unsigned* __restrict__ wt1r,
    unsigned* __restrict__ wt2l, unsigned* __restrict__ wt2r) {
  int i = blockIdx.x * 256 + threadIdx.x;
  union { _Float16 h[2]; unsigned u; } pk;
  if (i < 2048 * 2) {                       // layer-1 weights
    int which = i >> 11, j = i & 2047;
    int n = j >> 5, kp = j & 31;
    const float* W = which ? W1r : W1l;
    int k0 = 2 * kp, k1 = 2 * kp + 1;
    pk.h[0] = (_Float16)((k0 < IN_FEAT) ? W[k0 * HIDDEN + n] : 0.f);
    pk.h[1] = (_Float16)((k1 < IN_FEAT) ? W[k1 * HIDDEN + n] : 0.f);
    (which ? wt1r : wt1l)[j] = pk.u;
  } else if (i < 4096 + 2 * 1536) {         // layer-2 weights
    int j = i - 4096;
    int which = (j >= 1536), jj = which ? j - 1536 : j;
    int n = jj >> 5, kp = jj & 31;
    const float* W = which ? W2r : W2l;
    pk.h[0] = (_Float16)((n < N_CLASSES) ? W[(2 * kp) * N_CLASSES + n] : 0.f);
    pk.h[1] = (_Float16)((n < N_CLASSES) ? W[(2 * kp + 1) * N_CLASSES + n] : 0.f);
    (which ? wt2r : wt2l)[jj] = pk.u;
  }
}

// ---------------------------------------------------------------------------
// Counting-sort by dst.  Step 1: histogram of dst.
// ---------------------------------------------------------------------------
__global__ __launch_bounds__(256) void hist_kernel(
    const int* __restrict__ dst, int* __restrict__ counts) {
  int e = blockIdx.x * 256 + threadIdx.x;
  if (e < N_EDGES) atomicAdd(&counts[dst[e]], 1);
}

// Step 2a: per-chunk (2048 counts) reduction -> partial[49]
__global__ __launch_bounds__(256) void scanA_kernel(
    const int* __restrict__ counts, int* __restrict__ partial) {
  __shared__ int lds[256];
  int base = blockIdx.x * SCAN_CHUNK;
  int sum = 0;
  for (int i = threadIdx.x; i < SCAN_CHUNK; i += 256) {
    int idx = base + i;
    sum += (idx < N_NODES) ? counts[idx] : 0;
  }
  lds[threadIdx.x] = sum;
  __syncthreads();
  for (int off = 128; off >= 1; off >>= 1) {
    if (threadIdx.x < off) lds[threadIdx.x] += lds[threadIdx.x + off];
    __syncthreads();
  }
  if (threadIdx.x == 0) partial[blockIdx.x] = lds[0];
}

// Step 2b: single-wave exclusive scan of the 49 partials (in place).
__global__ __launch_bounds__(64) void scanB_kernel(
    int* __restrict__ partial, int* __restrict__ start) {
  int lane = threadIdx.x;
  int orig = (lane < SCAN_NBLK) ? partial[lane] : 0;
  int v = orig;
  for (int off = 1; off < 64; off <<= 1) {
    int t = __shfl_up(v, off);
    if (lane >= off) v += t;
  }
  if (lane < SCAN_NBLK) partial[lane] = v - orig;   // exclusive
  if (lane == 0) start[N_NODES] = N_EDGES;
}

// Step 2c: per-chunk exclusive scan + chunk offset -> start[] and cursor[].
__global__ __launch_bounds__(256) void scanC_kernel(
    const int* __restrict__ counts, const int* __restrict__ blockoff,
    int* __restrict__ start, int* __restrict__ cursor) {
  __shared__ int lds[256];
  const int PT = SCAN_CHUNK / 256;                  // 8
  int base = blockIdx.x * SCAN_CHUNK + threadIdx.x * PT;
  int c[PT];
  int tsum = 0;
#pragma unroll
  for (int k = 0; k < PT; ++k) {
    int idx = base + k;
    c[k] = (idx < N_NODES) ? counts[idx] : 0;
    tsum += c[k];
  }
  lds[threadIdx.x] = tsum;
  __syncthreads();
  for (int off = 1; off < 256; off <<= 1) {         // Hillis-Steele inclusive
    int t = (threadIdx.x >= (unsigned)off) ? lds[threadIdx.x - off] : 0;
    __syncthreads();
    lds[threadIdx.x] += t;
    __syncthreads();
  }
  int run = blockoff[blockIdx.x] + lds[threadIdx.x] - tsum;  // exclusive
#pragma unroll
  for (int k = 0; k < PT; ++k) {
    int idx = base + k;
    if (idx < N_NODES) { start[idx] = run; cursor[idx] = run; }
    run += c[k];
  }
}

// Bucket cursors: cursorB[b] = start[b*128]  (bucket = 128 consecutive nodes)
__global__ __launch_bounds__(256) void initB_kernel(
    const int* __restrict__ start, int* __restrict__ cursorB) {
  int b = blockIdx.x * 256 + threadIdx.x;
  if (b < N_BUCK) {
    int n = b << BUCK_SHIFT;
    cursorB[b] = start[n > N_NODES ? N_NODES : n];
  }
}

// Pass 1: bin (src,dst) pairs by dst-bucket.  Appends are sequential within
// each bucket region -> write lines fill before eviction.
__global__ __launch_bounds__(256) void binA_kernel(
    const int* __restrict__ src, const int* __restrict__ dst,
    int* __restrict__ cursorB, int2* __restrict__ tmp) {
  int e = blockIdx.x * 256 + threadIdx.x;
  if (e < N_EDGES) {
    int s = src[e], d = dst[e];
    int pos = atomicAdd(&cursorB[d >> BUCK_SHIFT], 1);
    tmp[pos] = make_int2(s, d);
  }
}

// Pass 2: final per-node scatter.  Each write lands in its bucket's ~8 KB
// output window (128 nodes * avg-degree * 4 B) -> L2-resident.
__global__ __launch_bounds__(256) void binB_kernel(
    const int2* __restrict__ tmp, int* __restrict__ cursor,
    int* __restrict__ sorted_src) {
  int e = blockIdx.x * 256 + threadIdx.x;
  if (e < N_EDGES) {
    int2 p = tmp[e];
    int pos = atomicAdd(&cursor[p.y], 1);
    sorted_src[pos] = p.x;
  }
}

// ---------------------------------------------------------------------------
// Gather 1: one wave per node, PURE gather (no weights, no LDS block).
//   aggh[node][64] = sum over neighbors of xh[src][0..63]   (f16 rows, 128 B)
// ---------------------------------------------------------------------------
__global__ __launch_bounds__(256) void gather1_kernel(
    const _Float16* __restrict__ xh, const int* __restrict__ start,
    const int* __restrict__ ssrc, _Float16* __restrict__ aggh) {
  int node = (blockIdx.x * 256 + threadIdx.x) >> 6;
  if (node >= N_NODES) return;
  int lane = threadIdx.x & 63;

  int s0 = start[node], s1 = start[node + 1];
  float a0 = 0.f, a1 = 0.f, a2 = 0.f, a3 = 0.f;

  for (int base = s0; base < s1; base += 64) {
    int cnt = s1 - base;
    if (cnt > 64) cnt = 64;
    int idxv = (lane < cnt) ? ssrc[base + lane] : 0;
    int j = 0;
    for (; j + 8 <= cnt; j += 8) {
      int i0 = __shfl(idxv, j + 0);
      int i1 = __shfl(idxv, j + 1);
      int i2 = __shfl(idxv, j + 2);
      int i3 = __shfl(idxv, j + 3);
      int i4 = __shfl(idxv, j + 4);
      int i5 = __shfl(idxv, j + 5);
      int i6 = __shfl(idxv, j + 6);
      int i7 = __shfl(idxv, j + 7);
      float v0 = (float)xh[i0 * 64 + lane];
      float v1 = (float)xh[i1 * 64 + lane];
      float v2 = (float)xh[i2 * 64 + lane];
      float v3 = (float)xh[i3 * 64 + lane];
      float v4 = (float)xh[i4 * 64 + lane];
      float v5 = (float)xh[i5 * 64 + lane];
      float v6 = (float)xh[i6 * 64 + lane];
      float v7 = (float)xh[i7 * 64 + lane];
      a0 += v0; a1 += v1; a2 += v2; a3 += v3;
      a0 += v4; a1 += v5; a2 += v6; a3 += v7;
    }
    for (; j < cnt; ++j) {
      int i0 = __shfl(idxv, j);
      a0 += (float)xh[i0 * 64 + lane];
    }
  }
  aggh[node * 64 + lane] = (_Float16)((a0 + a1) + (a2 + a3));
}

// ---------------------------------------------------------------------------
// MLP (MFMA, f16): one wave per 16-node tile.
//   h  = relu(agg@W1l + x@W1r + b1)   (internal, LDS only)
//   hl = h@W2l            -> hlh   [N][48] f16
//   op = h@W2r + b2       -> opart [N][48] f32
// ---------------------------------------------------------------------------
__global__ __launch_bounds__(256) void mlp1_kernel(
    const _Float16* __restrict__ aggh, const _Float16* __restrict__ xh,
    const unsigned* __restrict__ wt1l, const unsigned* __restrict__ wt1r,
    const unsigned* __restrict__ wt2l, const unsigned* __restrict__ wt2r,
    const float* __restrict__ b1, const float* __restrict__ b2,
    _Float16* __restrict__ hlh, float* __restrict__ opart) {
  __shared__ float sH[4][16][68];
  int wid = (blockIdx.x * 256 + threadIdx.x) >> 6;
  int w = (threadIdx.x >> 6) & 3;
  int lane = threadIdx.x & 63;
  int m = lane & 15, quad = lane >> 4;
  if (wid >= N_TILES) return;
  int tile = wid;

  half8 Aa[2], Ax[2];
#pragma unroll
  for (int s = 0; s < 2; ++s) {
    int off = (tile * 16 + m) * 64 + s * 32 + quad * 8;
    Aa[s] = *(const half8*)(aggh + off);
    Ax[s] = *(const half8*)(xh + off);
  }

#pragma unroll
  for (int t = 0; t < 4; ++t) {
    int n = t * 16 + m;
    half8 Bl0 = *(const half8*)(wt1l + n * 32 + quad * 4);
    half8 Bl1 = *(const half8*)(wt1l + n * 32 + 16 + quad * 4);
    half8 Br0 = *(const half8*)(wt1r + n * 32 + quad * 4);
    half8 Br1 = *(const half8*)(wt1r + n * 32 + 16 + quad * 4);
    float4v acc = {0.f, 0.f, 0.f, 0.f};
    acc = __builtin_amdgcn_mfma_f32_16x16x32_f16(Aa[0], Bl0, acc, 0, 0, 0);
    acc = __builtin_amdgcn_mfma_f32_16x16x32_f16(Aa[1], Bl1, acc, 0, 0, 0);
    acc = __builtin_amdgcn_mfma_f32_16x16x32_f16(Ax[0], Br0, acc, 0, 0, 0);
    acc = __builtin_amdgcn_mfma_f32_16x16x32_f16(Ax[1], Br1, acc, 0, 0, 0);
    float bv = b1[n];
#pragma unroll
    for (int r = 0; r < 4; ++r) {
      sH[w][quad * 4 + r][n] = fmaxf(acc[r] + bv, 0.f);
    }
  }

  half8 Ah[2];
#pragma unroll
  for (int s = 0; s < 2; ++s) {
    const float* pr = &sH[w][m][s * 32 + quad * 8];
    half8 A;
#pragma unroll
    for (int jj = 0; jj < 8; ++jj) A[jj] = (_Float16)pr[jj];
    Ah[s] = A;
  }

#pragma unroll
  for (int t = 0; t < 3; ++t) {
    int n = t * 16 + m;
    half8 Cl0 = *(const half8*)(wt2l + n * 32 + quad * 4);
    half8 Cl1 = *(const half8*)(wt2l + n * 32 + 16 + quad * 4);
    half8 Cr0 = *(const half8*)(wt2r + n * 32 + quad * 4);
    half8 Cr1 = *(const half8*)(wt2r + n * 32 + 16 + quad * 4);
    float4v acc2 = {0.f, 0.f, 0.f, 0.f};
    float4v acc3 = {0.f, 0.f, 0.f, 0.f};
    acc2 = __builtin_amdgcn_mfma_f32_16x16x32_f16(Ah[0], Cl0, acc2, 0, 0, 0);
    acc2 = __builtin_amdgcn_mfma_f32_16x16x32_f16(Ah[1], Cl1, acc2, 0, 0, 0);
    acc3 = __builtin_amdgcn_mfma_f32_16x16x32_f16(Ah[0], Cr0, acc3, 0, 0, 0);
    acc3 = __builtin_amdgcn_mfma_f32_16x16x32_f16(Ah[1], Cr1, acc3, 0, 0, 0);
    float bv = (n < N_CLASSES) ? b2[n] : 0.f;
#pragma unroll
    for (int r = 0; r < 4; ++r) {
      int row = tile * 16 + quad * 4 + r;
      hlh[row * NC48 + n] = (_Float16)acc2[r];
      opart[row * NC48 + n] = acc3[r] + bv;
    }
  }
}

// ---------------------------------------------------------------------------
// Gather 2 + softmax: one wave per node, pure gather of hl rows (f16, 96 B)
// ---------------------------------------------------------------------------
__global__ __launch_bounds__(256) void gather2_kernel(
    const _Float16* __restrict__ hlh, const float* __restrict__ opart,
    const int* __restrict__ start, const int* __restrict__ ssrc,
    float* __restrict__ out) {
  int node = (blockIdx.x * 256 + threadIdx.x) >> 6;
  if (node >= N_NODES) return;
  int lane = threadIdx.x & 63;
  bool gOK = (lane < NC48);
  bool cOK = (lane < N_CLASSES);

  float ov = cOK ? opart[node * NC48 + lane] : 0.f;

  int s0 = start[node], s1 = start[node + 1];
  float a0 = 0.f, a1 = 0.f, a2 = 0.f, a3 = 0.f;

  for (int base = s0; base < s1; base += 64) {
    int cnt = s1 - base;
    if (cnt > 64) cnt = 64;
    int idxv = (lane < cnt) ? ssrc[base + lane] : 0;
    int j = 0;
    for (; j + 8 <= cnt; j += 8) {
      int i0 = __shfl(idxv, j + 0);
      int i1 = __shfl(idxv, j + 1);
      int i2 = __shfl(idxv, j + 2);
      int i3 = __shfl(idxv, j + 3);
      int i4 = __shfl(idxv, j + 4);
      int i5 = __shfl(idxv, j + 5);
      int i6 = __shfl(idxv, j + 6);
      int i7 = __shfl(idxv, j + 7);
      if (gOK) {
        float v0 = (float)hlh[i0 * NC48 + lane];
        float v1 = (float)hlh[i1 * NC48 + lane];
        float v2 = (float)hlh[i2 * NC48 + lane];
        float v3 = (float)hlh[i3 * NC48 + lane];
        float v4 = (float)hlh[i4 * NC48 + lane];
        float v5 = (float)hlh[i5 * NC48 + lane];
        float v6 = (float)hlh[i6 * NC48 + lane];
        float v7 = (float)hlh[i7 * NC48 + lane];
        a0 += v0; a1 += v1; a2 += v2; a3 += v3;
        a0 += v4; a1 += v5; a2 += v6; a3 += v7;
      }
    }
    for (; j < cnt; ++j) {
      int i0 = __shfl(idxv, j);
      if (gOK) a0 += (float)hlh[i0 * NC48 + lane];
    }
  }

  float o = cOK ? (ov + (a0 + a1) + (a2 + a3)) : 0.f;

  float v = cOK ? o : -INFINITY;
#pragma unroll
  for (int off = 32; off >= 1; off >>= 1) v = fmaxf(v, __shfl_xor(v, off));
  float ex = cOK ? expf(o - v) : 0.0f;
  float s = ex;
#pragma unroll
  for (int off = 32; off >= 1; off >>= 1) s += __shfl_xor(s, off);
  float lse = logf(s);
  if (cOK) out[node * N_CLASSES + lane] = o - v - lse;
}

// ---------------------------------------------------------------------------
extern "C" void kernel_launch(void* const* d_in, const int* in_sizes, int n_in,
                              void* d_out, int out_size, void* d_ws, size_t ws_size,
                              hipStream_t stream) {
  const float* x   = (const float*)d_in[0];
  const float* W1l = (const float*)d_in[1];
  const float* W1r = (const float*)d_in[2];
  const float* b1  = (const float*)d_in[3];
  const float* W2l = (const float*)d_in[4];
  const float* W2r = (const float*)d_in[5];
  const float* b2  = (const float*)d_in[6];
  const int*   src = (const int*)d_in[7];
  const int*   dst = (const int*)d_in[8];
  float* out = (float*)d_out;

  // workspace layout (~62 MB):
  //   counts[N] start[N+1] cursor[N] partial[64] cursorB[1024] ssrc[E]
  //   wt1l[2048] wt1r[2048] wt2l[1536] wt2r[1536]   (u32)
  //   opart[N*48] f32  (binA/binB tmp pairs alias this region)
  //   xh[N*64] f16 | aggh[N*64] f16 | hlh[N*48] f16
  int* counts  = (int*)d_ws;
  int* start   = counts + N_NODES;
  int* cursor  = start + (N_NODES + 1);
  int* partial = cursor + N_NODES;
  int* cursorB = partial + 64;
  int* ssrc    = cursorB + 1024;
  unsigned* wt1l = (unsigned*)(ssrc + N_EDGES);
  unsigned* wt1r = wt1l + 2048;
  unsigned* wt2l = wt1r + 2048;
  unsigned* wt2r = wt2l + 1536;
  float* opart   = (float*)(wt2r + 1536);
  int2* tmp      = (int2*)opart;          // 12.8 MB alias (opart is 19.2 MB,
                                          // written only later by mlp1)
  _Float16* xh   = (_Float16*)(opart + (size_t)N_NODES * NC48);
  _Float16* aggh = xh + (size_t)N_NODES * 64;
  _Float16* hlh  = aggh + (size_t)N_NODES * 64;

  int eblocks = (N_EDGES + 255) / 256;

  zeroc_kernel<<<(N_NODES + 255) / 256, 256, 0, stream>>>(counts);
  packx_kernel<<<(N_NODES * 64 + 255) / 256, 256, 0, stream>>>(x, xh);
  packwts_kernel<<<(7168 + 255) / 256, 256, 0, stream>>>(
      W1l, W1r, W2l, W2r, wt1l, wt1r, wt2l, wt2r);
  hist_kernel<<<eblocks, 256, 0, stream>>>(dst, counts);
  scanA_kernel<<<SCAN_NBLK, 256, 0, stream>>>(counts, partial);
  scanB_kernel<<<1, 64, 0, stream>>>(partial, start);
  scanC_kernel<<<SCAN_NBLK, 256, 0, stream>>>(counts, partial, start, cursor);
  initB_kernel<<<(N_BUCK + 255) / 256, 256, 0, stream>>>(start, cursorB);
  binA_kernel<<<eblocks, 256, 0, stream>>>(src, dst, cursorB, tmp);
  binB_kernel<<<eblocks, 256, 0, stream>>>(tmp, cursor, ssrc);

  int gblocks = (N_NODES * 64 + 255) / 256;   // one wave per node
  gather1_kernel<<<gblocks, 256, 0, stream>>>(xh, start, ssrc, aggh);
  mlp1_kernel<<<(N_TILES * 64 + 255) / 256, 256, 0, stream>>>(
      aggh, xh, wt1l, wt1r, wt2l, wt2r, b1, b2, hlh, opart);
  gather2_kernel<<<gblocks, 256, 0, stream>>>(hlh, opart, start, ssrc, out);
}

// Round 10
// 386.246 us; speedup vs baseline: 1.9138x; 1.9138x over previous
//
#include <hip/hip_runtime.h>
#include <hip/hip_bf16.h>
#include <math.h>

#define N_NODES   100000
#define N_EDGES   1600000
#define IN_FEAT   50
#define HIDDEN    64
#define N_CLASSES 41
#define NC48      48          // padded class width
#define N_TILES   (N_NODES / 16)   // 6250 exactly

#define N_WIN     8
#define WIN_SZ    ((N_NODES + N_WIN - 1) / N_WIN)   // 12500

#define SCAN_CHUNK 2048
#define SCAN_NBLK  ((N_NODES + SCAN_CHUNK - 1) / SCAN_CHUNK)   // 49 (<=64)

typedef __attribute__((ext_vector_type(8))) _Float16 half8;
typedef __attribute__((ext_vector_type(4))) float   float4v;

// ---------------------------------------------------------------------------
// Zero the per-node counters.
// ---------------------------------------------------------------------------
__global__ __launch_bounds__(256) void zeroc_kernel(int* __restrict__ counts) {
  int i = blockIdx.x * 256 + threadIdx.x;
  if (i < N_NODES) counts[i] = 0;
}

// ---------------------------------------------------------------------------
// Prep A: x (f32 [N][50]) -> xh (f16 [N][64], k-padded with zeros)
// ---------------------------------------------------------------------------
__global__ __launch_bounds__(256) void packx_kernel(
    const float* __restrict__ x, _Float16* __restrict__ xh) {
  int i = blockIdx.x * 256 + threadIdx.x;
  if (i >= N_NODES * 64) return;
  int node = i >> 6, c = i & 63;
  xh[i] = (c < IN_FEAT) ? (_Float16)x[node * IN_FEAT + c] : (_Float16)0.f;
}

// ---------------------------------------------------------------------------
// Prep B: pack transposed f16-pair weights for MFMA B-fragments.
//   wt1l/wt1r: [64 n][32 kp]  from W1l/W1r [50][64]  (k>=50 zero)
//   wt2l/wt2r: [48 n][32 kp]  from W2l/W2r [64][41]  (n>=41 zero)
// ---------------------------------------------------------------------------
__global__ __launch_bounds__(256) void packwts_kernel(
    const float* __restrict__ W1l, const float* __restrict__ W1r,
    const float* __restrict__ W2l, const float* __restrict__ W2r,
    unsigned* __restrict__ wt1l, unsigned* __restrict__ wt1r,
    unsigned* __restrict__ wt2l, unsigned* __restrict__ wt2r) {
  int i = blockIdx.x * 256 + threadIdx.x;
  union { _Float16 h[2]; unsigned u; } pk;
  if (i < 2048 * 2) {                       // layer-1 weights
    int which = i >> 11, j = i & 2047;
    int n = j >> 5, kp = j & 31;
    const float* W = which ? W1r : W1l;
    int k0 = 2 * kp, k1 = 2 * kp + 1;
    pk.h[0] = (_Float16)((k0 < IN_FEAT) ? W[k0 * HIDDEN + n] : 0.f);
    pk.h[1] = (_Float16)((k1 < IN_FEAT) ? W[k1 * HIDDEN + n] : 0.f);
    (which ? wt1r : wt1l)[j] = pk.u;
  } else if (i < 4096 + 2 * 1536) {         // layer-2 weights
    int j = i - 4096;
    int which = (j >= 1536), jj = which ? j - 1536 : j;
    int n = jj >> 5, kp = jj & 31;
    const float* W = which ? W2r : W2l;
    pk.h[0] = (_Float16)((n < N_CLASSES) ? W[(2 * kp) * N_CLASSES + n] : 0.f);
    pk.h[1] = (_Float16)((n < N_CLASSES) ? W[(2 * kp + 1) * N_CLASSES + n] : 0.f);
    (which ? wt2r : wt2l)[jj] = pk.u;
  }
}

// ---------------------------------------------------------------------------
// Counting-sort by dst.  Step 1: histogram of dst.
// ---------------------------------------------------------------------------
__global__ __launch_bounds__(256) void hist_kernel(
    const int* __restrict__ dst, int* __restrict__ counts) {
  int e = blockIdx.x * 256 + threadIdx.x;
  if (e < N_EDGES) atomicAdd(&counts[dst[e]], 1);
}

// Step 2a: per-chunk (2048 counts) reduction -> partial[49]
__global__ __launch_bounds__(256) void scanA_kernel(
    const int* __restrict__ counts, int* __restrict__ partial) {
  __shared__ int lds[256];
  int base = blockIdx.x * SCAN_CHUNK;
  int sum = 0;
  for (int i = threadIdx.x; i < SCAN_CHUNK; i += 256) {
    int idx = base + i;
    sum += (idx < N_NODES) ? counts[idx] : 0;
  }
  lds[threadIdx.x] = sum;
  __syncthreads();
  for (int off = 128; off >= 1; off >>= 1) {
    if (threadIdx.x < off) lds[threadIdx.x] += lds[threadIdx.x + off];
    __syncthreads();
  }
  if (threadIdx.x == 0) partial[blockIdx.x] = lds[0];
}

// Step 2b: single-wave exclusive scan of the 49 partials (in place).
__global__ __launch_bounds__(64) void scanB_kernel(
    int* __restrict__ partial, int* __restrict__ start) {
  int lane = threadIdx.x;
  int orig = (lane < SCAN_NBLK) ? partial[lane] : 0;
  int v = orig;
  for (int off = 1; off < 64; off <<= 1) {
    int t = __shfl_up(v, off);
    if (lane >= off) v += t;
  }
  if (lane < SCAN_NBLK) partial[lane] = v - orig;   // exclusive
  if (lane == 0) start[N_NODES] = N_EDGES;
}

// Step 2c: per-chunk exclusive scan + chunk offset -> start[] and cursor[].
__global__ __launch_bounds__(256) void scanC_kernel(
    const int* __restrict__ counts, const int* __restrict__ blockoff,
    int* __restrict__ start, int* __restrict__ cursor) {
  __shared__ int lds[256];
  const int PT = SCAN_CHUNK / 256;                  // 8
  int base = blockIdx.x * SCAN_CHUNK + threadIdx.x * PT;
  int c[PT];
  int tsum = 0;
#pragma unroll
  for (int k = 0; k < PT; ++k) {
    int idx = base + k;
    c[k] = (idx < N_NODES) ? counts[idx] : 0;
    tsum += c[k];
  }
  lds[threadIdx.x] = tsum;
  __syncthreads();
  for (int off = 1; off < 256; off <<= 1) {         // Hillis-Steele inclusive
    int t = (threadIdx.x >= (unsigned)off) ? lds[threadIdx.x - off] : 0;
    __syncthreads();
    lds[threadIdx.x] += t;
    __syncthreads();
  }
  int run = blockoff[blockIdx.x] + lds[threadIdx.x] - tsum;  // exclusive
#pragma unroll
  for (int k = 0; k < PT; ++k) {
    int idx = base + k;
    if (idx < N_NODES) { start[idx] = run; cursor[idx] = run; }
    run += c[k];
  }
}

// ---------------------------------------------------------------------------
// XCD-affine windowed permute.  Window w = nodes [w*12500,(w+1)*12500);
// block b handles window b&7 (maps to XCD b%8 on MI355X round-robin) and
// edge-chunk rank b>>3.  Each window's scatter-writes + cursor atomics stay
// on ONE XCD: write lines co-fill in its L2 (~16 merges/line) instead of
// being bounced across 8 non-coherent L2s (R8: 106 MB HBM writes for 6.4 MB
// payload).  Costs an 8x re-read of dst, absorbed by L3.
// ---------------------------------------------------------------------------
__global__ __launch_bounds__(256) void permute8_kernel(
    const int* __restrict__ src, const int* __restrict__ dst,
    int* __restrict__ cursor, int* __restrict__ sorted_src) {
  int win  = blockIdx.x & 7;
  int rank = blockIdx.x >> 3;
  int e = rank * 256 + threadIdx.x;
  if (e >= N_EDGES) return;
  int d = dst[e];
  int lo = win * WIN_SZ;
  if (d >= lo && d < lo + WIN_SZ) {
    int pos = atomicAdd(&cursor[d], 1);
    sorted_src[pos] = src[e];
  }
}

// ---------------------------------------------------------------------------
// Gather 1: one wave per node, PURE gather.
//   aggh[node][64] = sum over neighbors of xh[src][0..63]   (f16 rows, 128 B)
// ---------------------------------------------------------------------------
__global__ __launch_bounds__(256) void gather1_kernel(
    const _Float16* __restrict__ xh, const int* __restrict__ start,
    const int* __restrict__ ssrc, _Float16* __restrict__ aggh) {
  int node = (blockIdx.x * 256 + threadIdx.x) >> 6;
  if (node >= N_NODES) return;
  int lane = threadIdx.x & 63;

  int s0 = start[node], s1 = start[node + 1];
  float a0 = 0.f, a1 = 0.f, a2 = 0.f, a3 = 0.f;

  for (int base = s0; base < s1; base += 64) {
    int cnt = s1 - base;
    if (cnt > 64) cnt = 64;
    int idxv = (lane < cnt) ? ssrc[base + lane] : 0;
    int j = 0;
    for (; j + 8 <= cnt; j += 8) {
      int i0 = __shfl(idxv, j + 0);
      int i1 = __shfl(idxv, j + 1);
      int i2 = __shfl(idxv, j + 2);
      int i3 = __shfl(idxv, j + 3);
      int i4 = __shfl(idxv, j + 4);
      int i5 = __shfl(idxv, j + 5);
      int i6 = __shfl(idxv, j + 6);
      int i7 = __shfl(idxv, j + 7);
      float v0 = (float)xh[i0 * 64 + lane];
      float v1 = (float)xh[i1 * 64 + lane];
      float v2 = (float)xh[i2 * 64 + lane];
      float v3 = (float)xh[i3 * 64 + lane];
      float v4 = (float)xh[i4 * 64 + lane];
      float v5 = (float)xh[i5 * 64 + lane];
      float v6 = (float)xh[i6 * 64 + lane];
      float v7 = (float)xh[i7 * 64 + lane];
      a0 += v0; a1 += v1; a2 += v2; a3 += v3;
      a0 += v4; a1 += v5; a2 += v6; a3 += v7;
    }
    for (; j < cnt; ++j) {
      int i0 = __shfl(idxv, j);
      a0 += (float)xh[i0 * 64 + lane];
    }
  }
  aggh[node * 64 + lane] = (_Float16)((a0 + a1) + (a2 + a3));
}

// ---------------------------------------------------------------------------
// MLP (MFMA, f16): one wave per 16-node tile.
//   h  = relu(agg@W1l + x@W1r + b1)   (internal, LDS only)
//   hl = h@W2l            -> hlh   [N][48] f16
//   op = h@W2r + b2       -> opart [N][48] f32
// ---------------------------------------------------------------------------
__global__ __launch_bounds__(256) void mlp1_kernel(
    const _Float16* __restrict__ aggh, const _Float16* __restrict__ xh,
    const unsigned* __restrict__ wt1l, const unsigned* __restrict__ wt1r,
    const unsigned* __restrict__ wt2l, const unsigned* __restrict__ wt2r,
    const float* __restrict__ b1, const float* __restrict__ b2,
    _Float16* __restrict__ hlh, float* __restrict__ opart) {
  __shared__ float sH[4][16][68];
  int wid = (blockIdx.x * 256 + threadIdx.x) >> 6;
  int w = (threadIdx.x >> 6) & 3;
  int lane = threadIdx.x & 63;
  int m = lane & 15, quad = lane >> 4;
  if (wid >= N_TILES) return;
  int tile = wid;

  half8 Aa[2], Ax[2];
#pragma unroll
  for (int s = 0; s < 2; ++s) {
    int off = (tile * 16 + m) * 64 + s * 32 + quad * 8;
    Aa[s] = *(const half8*)(aggh + off);
    Ax[s] = *(const half8*)(xh + off);
  }

#pragma unroll
  for (int t = 0; t < 4; ++t) {
    int n = t * 16 + m;
    half8 Bl0 = *(const half8*)(wt1l + n * 32 + quad * 4);
    half8 Bl1 = *(const half8*)(wt1l + n * 32 + 16 + quad * 4);
    half8 Br0 = *(const half8*)(wt1r + n * 32 + quad * 4);
    half8 Br1 = *(const half8*)(wt1r + n * 32 + 16 + quad * 4);
    float4v acc = {0.f, 0.f, 0.f, 0.f};
    acc = __builtin_amdgcn_mfma_f32_16x16x32_f16(Aa[0], Bl0, acc, 0, 0, 0);
    acc = __builtin_amdgcn_mfma_f32_16x16x32_f16(Aa[1], Bl1, acc, 0, 0, 0);
    acc = __builtin_amdgcn_mfma_f32_16x16x32_f16(Ax[0], Br0, acc, 0, 0, 0);
    acc = __builtin_amdgcn_mfma_f32_16x16x32_f16(Ax[1], Br1, acc, 0, 0, 0);
    float bv = b1[n];
#pragma unroll
    for (int r = 0; r < 4; ++r) {
      sH[w][quad * 4 + r][n] = fmaxf(acc[r] + bv, 0.f);
    }
  }

  half8 Ah[2];
#pragma unroll
  for (int s = 0; s < 2; ++s) {
    const float* pr = &sH[w][m][s * 32 + quad * 8];
    half8 A;
#pragma unroll
    for (int jj = 0; jj < 8; ++jj) A[jj] = (_Float16)pr[jj];
    Ah[s] = A;
  }

#pragma unroll
  for (int t = 0; t < 3; ++t) {
    int n = t * 16 + m;
    half8 Cl0 = *(const half8*)(wt2l + n * 32 + quad * 4);
    half8 Cl1 = *(const half8*)(wt2l + n * 32 + 16 + quad * 4);
    half8 Cr0 = *(const half8*)(wt2r + n * 32 + quad * 4);
    half8 Cr1 = *(const half8*)(wt2r + n * 32 + 16 + quad * 4);
    float4v acc2 = {0.f, 0.f, 0.f, 0.f};
    float4v acc3 = {0.f, 0.f, 0.f, 0.f};
    acc2 = __builtin_amdgcn_mfma_f32_16x16x32_f16(Ah[0], Cl0, acc2, 0, 0, 0);
    acc2 = __builtin_amdgcn_mfma_f32_16x16x32_f16(Ah[1], Cl1, acc2, 0, 0, 0);
    acc3 = __builtin_amdgcn_mfma_f32_16x16x32_f16(Ah[0], Cr0, acc3, 0, 0, 0);
    acc3 = __builtin_amdgcn_mfma_f32_16x16x32_f16(Ah[1], Cr1, acc3, 0, 0, 0);
    float bv = (n < N_CLASSES) ? b2[n] : 0.f;
#pragma unroll
    for (int r = 0; r < 4; ++r) {
      int row = tile * 16 + quad * 4 + r;
      hlh[row * NC48 + n] = (_Float16)acc2[r];
      opart[row * NC48 + n] = acc3[r] + bv;
    }
  }
}

// ---------------------------------------------------------------------------
// Gather 2 + softmax: one wave per node, pure gather of hl rows (f16, 96 B)
// ---------------------------------------------------------------------------
__global__ __launch_bounds__(256) void gather2_kernel(
    const _Float16* __restrict__ hlh, const float* __restrict__ opart,
    const int* __restrict__ start, const int* __restrict__ ssrc,
    float* __restrict__ out) {
  int node = (blockIdx.x * 256 + threadIdx.x) >> 6;
  if (node >= N_NODES) return;
  int lane = threadIdx.x & 63;
  bool gOK = (lane < NC48);
  bool cOK = (lane < N_CLASSES);

  float ov = cOK ? opart[node * NC48 + lane] : 0.f;

  int s0 = start[node], s1 = start[node + 1];
  float a0 = 0.f, a1 = 0.f, a2 = 0.f, a3 = 0.f;

  for (int base = s0; base < s1; base += 64) {
    int cnt = s1 - base;
    if (cnt > 64) cnt = 64;
    int idxv = (lane < cnt) ? ssrc[base + lane] : 0;
    int j = 0;
    for (; j + 8 <= cnt; j += 8) {
      int i0 = __shfl(idxv, j + 0);
      int i1 = __shfl(idxv, j + 1);
      int i2 = __shfl(idxv, j + 2);
      int i3 = __shfl(idxv, j + 3);
      int i4 = __shfl(idxv, j + 4);
      int i5 = __shfl(idxv, j + 5);
      int i6 = __shfl(idxv, j + 6);
      int i7 = __shfl(idxv, j + 7);
      if (gOK) {
        float v0 = (float)hlh[i0 * NC48 + lane];
        float v1 = (float)hlh[i1 * NC48 + lane];
        float v2 = (float)hlh[i2 * NC48 + lane];
        float v3 = (float)hlh[i3 * NC48 + lane];
        float v4 = (float)hlh[i4 * NC48 + lane];
        float v5 = (float)hlh[i5 * NC48 + lane];
        float v6 = (float)hlh[i6 * NC48 + lane];
        float v7 = (float)hlh[i7 * NC48 + lane];
        a0 += v0; a1 += v1; a2 += v2; a3 += v3;
        a0 += v4; a1 += v5; a2 += v6; a3 += v7;
      }
    }
    for (; j < cnt; ++j) {
      int i0 = __shfl(idxv, j);
      if (gOK) a0 += (float)hlh[i0 * NC48 + lane];
    }
  }

  float o = cOK ? (ov + (a0 + a1) + (a2 + a3)) : 0.f;

  float v = cOK ? o : -INFINITY;
#pragma unroll
  for (int off = 32; off >= 1; off >>= 1) v = fmaxf(v, __shfl_xor(v, off));
  float ex = cOK ? expf(o - v) : 0.0f;
  float s = ex;
#pragma unroll
  for (int off = 32; off >= 1; off >>= 1) s += __shfl_xor(s, off);
  float lse = logf(s);
  if (cOK) out[node * N_CLASSES + lane] = o - v - lse;
}

// ---------------------------------------------------------------------------
extern "C" void kernel_launch(void* const* d_in, const int* in_sizes, int n_in,
                              void* d_out, int out_size, void* d_ws, size_t ws_size,
                              hipStream_t stream) {
  const float* x   = (const float*)d_in[0];
  const float* W1l = (const float*)d_in[1];
  const float* W1r = (const float*)d_in[2];
  const float* b1  = (const float*)d_in[3];
  const float* W2l = (const float*)d_in[4];
  const float* W2r = (const float*)d_in[5];
  const float* b2  = (const float*)d_in[6];
  const int*   src = (const int*)d_in[7];
  const int*   dst = (const int*)d_in[8];
  float* out = (float*)d_out;

  // workspace layout (~62 MB):
  //   counts[N] start[N+1] cursor[N] partial[64] ssrc[E]
  //   wt1l[2048] wt1r[2048] wt2l[1536] wt2r[1536]   (u32)
  //   opart[N*48] f32 | xh[N*64] f16 | aggh[N*64] f16 | hlh[N*48] f16
  int* counts  = (int*)d_ws;
  int* start   = counts + N_NODES;
  int* cursor  = start + (N_NODES + 1);
  int* partial = cursor + N_NODES;
  int* ssrc    = partial + 64;
  unsigned* wt1l = (unsigned*)(ssrc + N_EDGES);
  unsigned* wt1r = wt1l + 2048;
  unsigned* wt2l = wt1r + 2048;
  unsigned* wt2r = wt2l + 1536;
  float* opart   = (float*)(wt2r + 1536);
  _Float16* xh   = (_Float16*)(opart + (size_t)N_NODES * NC48);
  _Float16* aggh = xh + (size_t)N_NODES * 64;
  _Float16* hlh  = aggh + (size_t)N_NODES * 64;

  int eblocks = (N_EDGES + 255) / 256;   // 6250

  zeroc_kernel<<<(N_NODES + 255) / 256, 256, 0, stream>>>(counts);
  packx_kernel<<<(N_NODES * 64 + 255) / 256, 256, 0, stream>>>(x, xh);
  packwts_kernel<<<(7168 + 255) / 256, 256, 0, stream>>>(
      W1l, W1r, W2l, W2r, wt1l, wt1r, wt2l, wt2r);
  hist_kernel<<<eblocks, 256, 0, stream>>>(dst, counts);
  scanA_kernel<<<SCAN_NBLK, 256, 0, stream>>>(counts, partial);
  scanB_kernel<<<1, 64, 0, stream>>>(partial, start);
  scanC_kernel<<<SCAN_NBLK, 256, 0, stream>>>(counts, partial, start, cursor);
  permute8_kernel<<<eblocks * N_WIN, 256, 0, stream>>>(src, dst, cursor, ssrc);

  int gblocks = (N_NODES * 64 + 255) / 256;   // one wave per node
  gather1_kernel<<<gblocks, 256, 0, stream>>>(xh, start, ssrc, aggh);
  mlp1_kernel<<<(N_TILES * 64 + 255) / 256, 256, 0, stream>>>(
      aggh, xh, wt1l, wt1r, wt2l, wt2r, b1, b2, hlh, opart);
  gather2_kernel<<<gblocks, 256, 0, stream>>>(hlh, opart, start, ssrc, out);
}

// Round 12
// 385.668 us; speedup vs baseline: 1.9167x; 1.0015x over previous
//
#include <hip/hip_runtime.h>
#include <hip/hip_bf16.h>
#include <math.h>

#define N_NODES   100000
#define N_EDGES   1600000
#define IN_FEAT   50
#define HIDDEN    64
#define N_CLASSES 41
#define NC48      48          // padded class width
#define N_TILES   (N_NODES / 16)   // 6250 exactly

#define N_WIN     8
#define WIN_SZ    ((N_NODES + N_WIN - 1) / N_WIN)   // 12500

#define SCAN_CHUNK 2048
#define SCAN_NBLK  ((N_NODES + SCAN_CHUNK - 1) / SCAN_CHUNK)   // 49 (<=64)

typedef __attribute__((ext_vector_type(8))) _Float16 half8;
typedef __attribute__((ext_vector_type(4))) float   float4v;

union f16pk { _Float16 h[2]; unsigned u; };

// index clamp: any value outside [0,N_NODES) becomes 0 (defensive; see R11)
__device__ __forceinline__ int clampidx(int i) {
  return ((unsigned)i < (unsigned)N_NODES) ? i : 0;
}

// ---------------------------------------------------------------------------
// Zero the per-node counters.
// ---------------------------------------------------------------------------
__global__ __launch_bounds__(256) void zeroc_kernel(int* __restrict__ counts) {
  int i = blockIdx.x * 256 + threadIdx.x;
  if (i < N_NODES) counts[i] = 0;
}

// ---------------------------------------------------------------------------
// Prep A: x (f32 [N][50]) -> xh (f16 [N][64], k-padded with zeros)
// ---------------------------------------------------------------------------
__global__ __launch_bounds__(256) void packx_kernel(
    const float* __restrict__ x, _Float16* __restrict__ xh) {
  int i = blockIdx.x * 256 + threadIdx.x;
  if (i >= N_NODES * 64) return;
  int node = i >> 6, c = i & 63;
  xh[i] = (c < IN_FEAT) ? (_Float16)x[node * IN_FEAT + c] : (_Float16)0.f;
}

// ---------------------------------------------------------------------------
// Prep B: pack transposed f16-pair weights for MFMA B-fragments.
// ---------------------------------------------------------------------------
__global__ __launch_bounds__(256) void packwts_kernel(
    const float* __restrict__ W1l, const float* __restrict__ W1r,
    const float* __restrict__ W2l, const float* __restrict__ W2r,
    unsigned* __restrict__ wt1l, unsigned* __restrict__ wt1r,
    unsigned* __restrict__ wt2l, unsigned* __restrict__ wt2r) {
  int i = blockIdx.x * 256 + threadIdx.x;
  f16pk pk;
  if (i < 2048 * 2) {                       // layer-1 weights
    int which = i >> 11, j = i & 2047;
    int n = j >> 5, kp = j & 31;
    const float* W = which ? W1r : W1l;
    int k0 = 2 * kp, k1 = 2 * kp + 1;
    pk.h[0] = (_Float16)((k0 < IN_FEAT) ? W[k0 * HIDDEN + n] : 0.f);
    pk.h[1] = (_Float16)((k1 < IN_FEAT) ? W[k1 * HIDDEN + n] : 0.f);
    (which ? wt1r : wt1l)[j] = pk.u;
  } else if (i < 4096 + 2 * 1536) {         // layer-2 weights
    int j = i - 4096;
    int which = (j >= 1536), jj = which ? j - 1536 : j;
    int n = jj >> 5, kp = jj & 31;
    const float* W = which ? W2r : W2l;
    pk.h[0] = (_Float16)((n < N_CLASSES) ? W[(2 * kp) * N_CLASSES + n] : 0.f);
    pk.h[1] = (_Float16)((n < N_CLASSES) ? W[(2 * kp + 1) * N_CLASSES + n] : 0.f);
    (which ? wt2r : wt2l)[jj] = pk.u;
  }
}

// ---------------------------------------------------------------------------
// Counting-sort by dst.  Step 1: histogram of dst.
// ---------------------------------------------------------------------------
__global__ __launch_bounds__(256) void hist_kernel(
    const int* __restrict__ dst, int* __restrict__ counts) {
  int e = blockIdx.x * 256 + threadIdx.x;
  if (e < N_EDGES) atomicAdd(&counts[dst[e]], 1);
}

// Step 2a: per-chunk (2048 counts) reduction -> partial[49]
__global__ __launch_bounds__(256) void scanA_kernel(
    const int* __restrict__ counts, int* __restrict__ partial) {
  __shared__ int lds[256];
  int base = blockIdx.x * SCAN_CHUNK;
  int sum = 0;
  for (int i = threadIdx.x; i < SCAN_CHUNK; i += 256) {
    int idx = base + i;
    sum += (idx < N_NODES) ? counts[idx] : 0;
  }
  lds[threadIdx.x] = sum;
  __syncthreads();
  for (int off = 128; off >= 1; off >>= 1) {
    if (threadIdx.x < off) lds[threadIdx.x] += lds[threadIdx.x + off];
    __syncthreads();
  }
  if (threadIdx.x == 0) partial[blockIdx.x] = lds[0];
}

// Step 2b: single-wave exclusive scan of the 49 partials (in place).
__global__ __launch_bounds__(64) void scanB_kernel(
    int* __restrict__ partial, int* __restrict__ start) {
  int lane = threadIdx.x;
  int orig = (lane < SCAN_NBLK) ? partial[lane] : 0;
  int v = orig;
  for (int off = 1; off < 64; off <<= 1) {
    int t = __shfl_up(v, off);
    if (lane >= off) v += t;
  }
  if (lane < SCAN_NBLK) partial[lane] = v - orig;   // exclusive
  if (lane == 0) start[N_NODES] = N_EDGES;
}

// Step 2c: per-chunk exclusive scan + chunk offset -> start[] and cursor[].
__global__ __launch_bounds__(256) void scanC_kernel(
    const int* __restrict__ counts, const int* __restrict__ blockoff,
    int* __restrict__ start, int* __restrict__ cursor) {
  __shared__ int lds[256];
  const int PT = SCAN_CHUNK / 256;                  // 8
  int base = blockIdx.x * SCAN_CHUNK + threadIdx.x * PT;
  int c[PT];
  int tsum = 0;
#pragma unroll
  for (int k = 0; k < PT; ++k) {
    int idx = base + k;
    c[k] = (idx < N_NODES) ? counts[idx] : 0;
    tsum += c[k];
  }
  lds[threadIdx.x] = tsum;
  __syncthreads();
  for (int off = 1; off < 256; off <<= 1) {         // Hillis-Steele inclusive
    int t = (threadIdx.x >= (unsigned)off) ? lds[threadIdx.x - off] : 0;
    __syncthreads();
    lds[threadIdx.x] += t;
    __syncthreads();
  }
  int run = blockoff[blockIdx.x] + lds[threadIdx.x] - tsum;  // exclusive
#pragma unroll
  for (int k = 0; k < PT; ++k) {
    int idx = base + k;
    if (idx < N_NODES) { start[idx] = run; cursor[idx] = run; }
    run += c[k];
  }
}

// ---------------------------------------------------------------------------
// XCD-affine windowed permute (R10: 130 -> 68 us vs flat permute).
// ---------------------------------------------------------------------------
__global__ __launch_bounds__(256) void permute8_kernel(
    const int* __restrict__ src, const int* __restrict__ dst,
    int* __restrict__ cursor, int* __restrict__ sorted_src) {
  int win  = blockIdx.x & 7;
  int rank = blockIdx.x >> 3;
  int e = rank * 256 + threadIdx.x;
  if (e >= N_EDGES) return;
  int d = dst[e];
  int lo = win * WIN_SZ;
  if (d >= lo && d < lo + WIN_SZ) {
    int pos = atomicAdd(&cursor[d], 1);
    sorted_src[pos] = src[e];
  }
}

// ---------------------------------------------------------------------------
// Gather 1 (dword-paired): lanes 0-31 row A, 32-63 row B, each lane loads a
// 4 B dword (2 f16 features) -> 16 rows in flight per 8-deep unroll.
// All gathered indices clamped to [0,N_NODES).
// ---------------------------------------------------------------------------
__global__ __launch_bounds__(256) void gather1_kernel(
    const unsigned* __restrict__ xw,       // xh as dwords [N][32]
    const int* __restrict__ start, const int* __restrict__ ssrc,
    unsigned* __restrict__ aggw) {         // aggh as dwords [N][32]
  int node = (blockIdx.x * 256 + threadIdx.x) >> 6;
  if (node >= N_NODES) return;
  int lane = threadIdx.x & 63;
  int col = lane & 31;
  int rowsel = lane >> 5;

  int s0 = start[node], s1 = start[node + 1];
  float aL0 = 0.f, aH0 = 0.f, aL1 = 0.f, aH1 = 0.f;

  for (int base = s0; base < s1; base += 64) {
    int cnt = s1 - base;
    if (cnt > 64) cnt = 64;
    int idxv = (lane < cnt) ? ssrc[base + lane] : 0;
    int j = 0;
    for (; j + 16 <= cnt; j += 16) {
      int i0 = clampidx(__shfl(idxv, j + 0 + rowsel));
      int i1 = clampidx(__shfl(idxv, j + 2 + rowsel));
      int i2 = clampidx(__shfl(idxv, j + 4 + rowsel));
      int i3 = clampidx(__shfl(idxv, j + 6 + rowsel));
      int i4 = clampidx(__shfl(idxv, j + 8 + rowsel));
      int i5 = clampidx(__shfl(idxv, j + 10 + rowsel));
      int i6 = clampidx(__shfl(idxv, j + 12 + rowsel));
      int i7 = clampidx(__shfl(idxv, j + 14 + rowsel));
      unsigned u0 = xw[i0 * 32 + col];
      unsigned u1 = xw[i1 * 32 + col];
      unsigned u2 = xw[i2 * 32 + col];
      unsigned u3 = xw[i3 * 32 + col];
      unsigned u4 = xw[i4 * 32 + col];
      unsigned u5 = xw[i5 * 32 + col];
      unsigned u6 = xw[i6 * 32 + col];
      unsigned u7 = xw[i7 * 32 + col];
      f16pk p;
      p.u = u0; aL0 += (float)p.h[0]; aH0 += (float)p.h[1];
      p.u = u1; aL1 += (float)p.h[0]; aH1 += (float)p.h[1];
      p.u = u2; aL0 += (float)p.h[0]; aH0 += (float)p.h[1];
      p.u = u3; aL1 += (float)p.h[0]; aH1 += (float)p.h[1];
      p.u = u4; aL0 += (float)p.h[0]; aH0 += (float)p.h[1];
      p.u = u5; aL1 += (float)p.h[0]; aH1 += (float)p.h[1];
      p.u = u6; aL0 += (float)p.h[0]; aH0 += (float)p.h[1];
      p.u = u7; aL1 += (float)p.h[0]; aH1 += (float)p.h[1];
    }
    for (; j + 2 <= cnt; j += 2) {
      int i0 = clampidx(__shfl(idxv, j + rowsel));
      f16pk p; p.u = xw[i0 * 32 + col];
      aL0 += (float)p.h[0]; aH0 += (float)p.h[1];
    }
    if (j < cnt) {
      int i0 = clampidx(__shfl(idxv, j));
      if (rowsel == 0) {
        f16pk p; p.u = xw[i0 * 32 + col];
        aL0 += (float)p.h[0]; aH0 += (float)p.h[1];
      }
    }
  }
  float sL = aL0 + aL1, sH = aH0 + aH1;
  sL += __shfl_xor(sL, 32);
  sH += __shfl_xor(sH, 32);
  if (rowsel == 0) {
    f16pk pk;
    pk.h[0] = (_Float16)sL;
    pk.h[1] = (_Float16)sH;
    aggw[node * 32 + col] = pk.u;
  }
}

// ---------------------------------------------------------------------------
// MLP (MFMA, f16): one wave per 16-node tile.  (unchanged from R8/R10)
// ---------------------------------------------------------------------------
__global__ __launch_bounds__(256) void mlp1_kernel(
    const _Float16* __restrict__ aggh, const _Float16* __restrict__ xh,
    const unsigned* __restrict__ wt1l, const unsigned* __restrict__ wt1r,
    const unsigned* __restrict__ wt2l, const unsigned* __restrict__ wt2r,
    const float* __restrict__ b1, const float* __restrict__ b2,
    _Float16* __restrict__ hlh, float* __restrict__ opart) {
  __shared__ float sH[4][16][68];
  int wid = (blockIdx.x * 256 + threadIdx.x) >> 6;
  int w = (threadIdx.x >> 6) & 3;
  int lane = threadIdx.x & 63;
  int m = lane & 15, quad = lane >> 4;
  if (wid >= N_TILES) return;
  int tile = wid;

  half8 Aa[2], Ax[2];
#pragma unroll
  for (int s = 0; s < 2; ++s) {
    int off = (tile * 16 + m) * 64 + s * 32 + quad * 8;
    Aa[s] = *(const half8*)(aggh + off);
    Ax[s] = *(const half8*)(xh + off);
  }

#pragma unroll
  for (int t = 0; t < 4; ++t) {
    int n = t * 16 + m;
    half8 Bl0 = *(const half8*)(wt1l + n * 32 + quad * 4);
    half8 Bl1 = *(const half8*)(wt1l + n * 32 + 16 + quad * 4);
    half8 Br0 = *(const half8*)(wt1r + n * 32 + quad * 4);
    half8 Br1 = *(const half8*)(wt1r + n * 32 + 16 + quad * 4);
    float4v acc = {0.f, 0.f, 0.f, 0.f};
    acc = __builtin_amdgcn_mfma_f32_16x16x32_f16(Aa[0], Bl0, acc, 0, 0, 0);
    acc = __builtin_amdgcn_mfma_f32_16x16x32_f16(Aa[1], Bl1, acc, 0, 0, 0);
    acc = __builtin_amdgcn_mfma_f32_16x16x32_f16(Ax[0], Br0, acc, 0, 0, 0);
    acc = __builtin_amdgcn_mfma_f32_16x16x32_f16(Ax[1], Br1, acc, 0, 0, 0);
    float bv = b1[n];
#pragma unroll
    for (int r = 0; r < 4; ++r) {
      sH[w][quad * 4 + r][n] = fmaxf(acc[r] + bv, 0.f);
    }
  }

  half8 Ah[2];
#pragma unroll
  for (int s = 0; s < 2; ++s) {
    const float* pr = &sH[w][m][s * 32 + quad * 8];
    half8 A;
#pragma unroll
    for (int jj = 0; jj < 8; ++jj) A[jj] = (_Float16)pr[jj];
    Ah[s] = A;
  }

#pragma unroll
  for (int t = 0; t < 3; ++t) {
    int n = t * 16 + m;
    half8 Cl0 = *(const half8*)(wt2l + n * 32 + quad * 4);
    half8 Cl1 = *(const half8*)(wt2l + n * 32 + 16 + quad * 4);
    half8 Cr0 = *(const half8*)(wt2r + n * 32 + quad * 4);
    half8 Cr1 = *(const half8*)(wt2r + n * 32 + 16 + quad * 4);
    float4v acc2 = {0.f, 0.f, 0.f, 0.f};
    float4v acc3 = {0.f, 0.f, 0.f, 0.f};
    acc2 = __builtin_amdgcn_mfma_f32_16x16x32_f16(Ah[0], Cl0, acc2, 0, 0, 0);
    acc2 = __builtin_amdgcn_mfma_f32_16x16x32_f16(Ah[1], Cl1, acc2, 0, 0, 0);
    acc3 = __builtin_amdgcn_mfma_f32_16x16x32_f16(Ah[0], Cr0, acc3, 0, 0, 0);
    acc3 = __builtin_amdgcn_mfma_f32_16x16x32_f16(Ah[1], Cr1, acc3, 0, 0, 0);
    float bv = (n < N_CLASSES) ? b2[n] : 0.f;
#pragma unroll
    for (int r = 0; r < 4; ++r) {
      int row = tile * 16 + quad * 4 + r;
      hlh[row * NC48 + n] = (_Float16)acc2[r];
      opart[row * NC48 + n] = acc3[r] + bv;
    }
  }
}

// ---------------------------------------------------------------------------
// Gather 2 + softmax (dword-paired): rows are 48 f16 = 24 dwords.
// ---------------------------------------------------------------------------
__global__ __launch_bounds__(256) void gather2_kernel(
    const unsigned* __restrict__ hlw,      // hlh as dwords [N][24]
    const float* __restrict__ opart,
    const int* __restrict__ start, const int* __restrict__ ssrc,
    float* __restrict__ out) {
  int node = (blockIdx.x * 256 + threadIdx.x) >> 6;
  if (node >= N_NODES) return;
  int lane = threadIdx.x & 63;
  int col = lane & 31;
  int rowsel = lane >> 5;
  bool colOK = (col < 24);

  float o0p = 0.f, o1p = 0.f;
  if (lane < 24) {
    o0p = opart[node * NC48 + 2 * lane];
    o1p = opart[node * NC48 + 2 * lane + 1];
  }

  int s0 = start[node], s1 = start[node + 1];
  float aL0 = 0.f, aH0 = 0.f, aL1 = 0.f, aH1 = 0.f;

  for (int base = s0; base < s1; base += 64) {
    int cnt = s1 - base;
    if (cnt > 64) cnt = 64;
    int idxv = (lane < cnt) ? ssrc[base + lane] : 0;
    int j = 0;
    for (; j + 16 <= cnt; j += 16) {
      int i0 = clampidx(__shfl(idxv, j + 0 + rowsel));
      int i1 = clampidx(__shfl(idxv, j + 2 + rowsel));
      int i2 = clampidx(__shfl(idxv, j + 4 + rowsel));
      int i3 = clampidx(__shfl(idxv, j + 6 + rowsel));
      int i4 = clampidx(__shfl(idxv, j + 8 + rowsel));
      int i5 = clampidx(__shfl(idxv, j + 10 + rowsel));
      int i6 = clampidx(__shfl(idxv, j + 12 + rowsel));
      int i7 = clampidx(__shfl(idxv, j + 14 + rowsel));
      if (colOK) {
        unsigned u0 = hlw[i0 * 24 + col];
        unsigned u1 = hlw[i1 * 24 + col];
        unsigned u2 = hlw[i2 * 24 + col];
        unsigned u3 = hlw[i3 * 24 + col];
        unsigned u4 = hlw[i4 * 24 + col];
        unsigned u5 = hlw[i5 * 24 + col];
        unsigned u6 = hlw[i6 * 24 + col];
        unsigned u7 = hlw[i7 * 24 + col];
        f16pk p;
        p.u = u0; aL0 += (float)p.h[0]; aH0 += (float)p.h[1];
        p.u = u1; aL1 += (float)p.h[0]; aH1 += (float)p.h[1];
        p.u = u2; aL0 += (float)p.h[0]; aH0 += (float)p.h[1];
        p.u = u3; aL1 += (float)p.h[0]; aH1 += (float)p.h[1];
        p.u = u4; aL0 += (float)p.h[0]; aH0 += (float)p.h[1];
        p.u = u5; aL1 += (float)p.h[0]; aH1 += (float)p.h[1];
        p.u = u6; aL0 += (float)p.h[0]; aH0 += (float)p.h[1];
        p.u = u7; aL1 += (float)p.h[0]; aH1 += (float)p.h[1];
      }
    }
    for (; j + 2 <= cnt; j += 2) {
      int i0 = clampidx(__shfl(idxv, j + rowsel));
      if (colOK) {
        f16pk p; p.u = hlw[i0 * 24 + col];
        aL0 += (float)p.h[0]; aH0 += (float)p.h[1];
      }
    }
    if (j < cnt) {
      int i0 = clampidx(__shfl(idxv, j));
      if (rowsel == 0 && colOK) {
        f16pk p; p.u = hlw[i0 * 24 + col];
        aL0 += (float)p.h[0]; aH0 += (float)p.h[1];
      }
    }
  }
  float sL = aL0 + aL1, sH = aH0 + aH1;
  sL += __shfl_xor(sL, 32);
  sH += __shfl_xor(sH, 32);

  bool act = (lane < 24);
  int f0 = 2 * lane, f1 = 2 * lane + 1;
  bool v0 = act && (f0 < N_CLASSES);
  bool v1 = act && (f1 < N_CLASSES);
  float o0 = v0 ? (o0p + sL) : 0.f;
  float o1 = v1 ? (o1p + sH) : 0.f;

  float vm = fmaxf(v0 ? o0 : -INFINITY, v1 ? o1 : -INFINITY);
#pragma unroll
  for (int off = 32; off >= 1; off >>= 1) vm = fmaxf(vm, __shfl_xor(vm, off));
  float e0 = v0 ? expf(o0 - vm) : 0.f;
  float e1 = v1 ? expf(o1 - vm) : 0.f;
  float s = e0 + e1;
#pragma unroll
  for (int off = 32; off >= 1; off >>= 1) s += __shfl_xor(s, off);
  float lse = logf(s);
  if (v0) out[node * N_CLASSES + f0] = o0 - vm - lse;
  if (v1) out[node * N_CLASSES + f1] = o1 - vm - lse;
}

// ---------------------------------------------------------------------------
extern "C" void kernel_launch(void* const* d_in, const int* in_sizes, int n_in,
                              void* d_out, int out_size, void* d_ws, size_t ws_size,
                              hipStream_t stream) {
  const float* x   = (const float*)d_in[0];
  const float* W1l = (const float*)d_in[1];
  const float* W1r = (const float*)d_in[2];
  const float* b1  = (const float*)d_in[3];
  const float* W2l = (const float*)d_in[4];
  const float* W2r = (const float*)d_in[5];
  const float* b2  = (const float*)d_in[6];
  const int*   src = (const int*)d_in[7];
  const int*   dst = (const int*)d_in[8];
  float* out = (float*)d_out;

  int* counts  = (int*)d_ws;
  int* start   = counts + N_NODES;
  int* cursor  = start + (N_NODES + 1);
  int* partial = cursor + N_NODES;
  int* ssrc    = partial + 64;
  unsigned* wt1l = (unsigned*)(ssrc + N_EDGES);
  unsigned* wt1r = wt1l + 2048;
  unsigned* wt2l = wt1r + 2048;
  unsigned* wt2r = wt2l + 1536;
  float* opart   = (float*)(wt2r + 1536);
  _Float16* xh   = (_Float16*)(opart + (size_t)N_NODES * NC48);
  _Float16* aggh = xh + (size_t)N_NODES * 64;
  _Float16* hlh  = aggh + (size_t)N_NODES * 64;

  int eblocks = (N_EDGES + 255) / 256;   // 6250

  zeroc_kernel<<<(N_NODES + 255) / 256, 256, 0, stream>>>(counts);
  packx_kernel<<<(N_NODES * 64 + 255) / 256, 256, 0, stream>>>(x, xh);
  packwts_kernel<<<(7168 + 255) / 256, 256, 0, stream>>>(
      W1l, W1r, W2l, W2r, wt1l, wt1r, wt2l, wt2r);
  hist_kernel<<<eblocks, 256, 0, stream>>>(dst, counts);
  scanA_kernel<<<SCAN_NBLK, 256, 0, stream>>>(counts, partial);
  scanB_kernel<<<1, 64, 0, stream>>>(partial, start);
  scanC_kernel<<<SCAN_NBLK, 256, 0, stream>>>(counts, partial, start, cursor);
  permute8_kernel<<<eblocks * N_WIN, 256, 0, stream>>>(src, dst, cursor, ssrc);

  int gblocks = (N_NODES * 64 + 255) / 256;   // one wave per node
  gather1_kernel<<<gblocks, 256, 0, stream>>>(
      (const unsigned*)xh, start, ssrc, (unsigned*)aggh);
  mlp1_kernel<<<(N_TILES * 64 + 255) / 256, 256, 0, stream>>>(
      aggh, xh, wt1l, wt1r, wt2l, wt2r, b1, b2, hlh, opart);
  gather2_kernel<<<gblocks, 256, 0, stream>>>(
      (const unsigned*)hlh, opart, start, ssrc, out);
}

// Round 13
// 366.817 us; speedup vs baseline: 2.0152x; 1.0514x over previous
//
#include <hip/hip_runtime.h>
#include <hip/hip_bf16.h>
#include <math.h>

#define N_NODES   100000
#define N_EDGES   1600000
#define IN_FEAT   50
#define HIDDEN    64
#define N_CLASSES 41
#define NC48      48          // padded class width
#define N_TILES   (N_NODES / 16)   // 6250 exactly

#define N_WIN     8
#define WIN_SZ    ((N_NODES + N_WIN - 1) / N_WIN)   // 12500

#define SCAN_CHUNK 2048
#define SCAN_NBLK  ((N_NODES + SCAN_CHUNK - 1) / SCAN_CHUNK)   // 49 (<=64)

typedef __attribute__((ext_vector_type(8))) _Float16 half8;
typedef __attribute__((ext_vector_type(4))) float   float4v;

union f16pk { _Float16 h[2]; unsigned u; };
union quadpk { uint4 v; _Float16 h[8]; };

// index clamp: any value outside [0,N_NODES) becomes 0 (defensive; see R11)
__device__ __forceinline__ int clampidx(int i) {
  return ((unsigned)i < (unsigned)N_NODES) ? i : 0;
}

// ---------------------------------------------------------------------------
// Zero the per-node counters.
// ---------------------------------------------------------------------------
__global__ __launch_bounds__(256) void zeroc_kernel(int* __restrict__ counts) {
  int i = blockIdx.x * 256 + threadIdx.x;
  if (i < N_NODES) counts[i] = 0;
}

// ---------------------------------------------------------------------------
// Prep A: x (f32 [N][50]) -> xh (f16 [N][64], k-padded with zeros)
// ---------------------------------------------------------------------------
__global__ __launch_bounds__(256) void packx_kernel(
    const float* __restrict__ x, _Float16* __restrict__ xh) {
  int i = blockIdx.x * 256 + threadIdx.x;
  if (i >= N_NODES * 64) return;
  int node = i >> 6, c = i & 63;
  xh[i] = (c < IN_FEAT) ? (_Float16)x[node * IN_FEAT + c] : (_Float16)0.f;
}

// ---------------------------------------------------------------------------
// Prep B: pack transposed f16-pair weights for MFMA B-fragments.
// ---------------------------------------------------------------------------
__global__ __launch_bounds__(256) void packwts_kernel(
    const float* __restrict__ W1l, const float* __restrict__ W1r,
    const float* __restrict__ W2l, const float* __restrict__ W2r,
    unsigned* __restrict__ wt1l, unsigned* __restrict__ wt1r,
    unsigned* __restrict__ wt2l, unsigned* __restrict__ wt2r) {
  int i = blockIdx.x * 256 + threadIdx.x;
  f16pk pk;
  if (i < 2048 * 2) {                       // layer-1 weights
    int which = i >> 11, j = i & 2047;
    int n = j >> 5, kp = j & 31;
    const float* W = which ? W1r : W1l;
    int k0 = 2 * kp, k1 = 2 * kp + 1;
    pk.h[0] = (_Float16)((k0 < IN_FEAT) ? W[k0 * HIDDEN + n] : 0.f);
    pk.h[1] = (_Float16)((k1 < IN_FEAT) ? W[k1 * HIDDEN + n] : 0.f);
    (which ? wt1r : wt1l)[j] = pk.u;
  } else if (i < 4096 + 2 * 1536) {         // layer-2 weights
    int j = i - 4096;
    int which = (j >= 1536), jj = which ? j - 1536 : j;
    int n = jj >> 5, kp = jj & 31;
    const float* W = which ? W2r : W2l;
    pk.h[0] = (_Float16)((n < N_CLASSES) ? W[(2 * kp) * N_CLASSES + n] : 0.f);
    pk.h[1] = (_Float16)((n < N_CLASSES) ? W[(2 * kp + 1) * N_CLASSES + n] : 0.f);
    (which ? wt2r : wt2l)[jj] = pk.u;
  }
}

// ---------------------------------------------------------------------------
// Counting-sort by dst.  Step 1: histogram of dst.
// ---------------------------------------------------------------------------
__global__ __launch_bounds__(256) void hist_kernel(
    const int* __restrict__ dst, int* __restrict__ counts) {
  int e = blockIdx.x * 256 + threadIdx.x;
  if (e < N_EDGES) atomicAdd(&counts[dst[e]], 1);
}

// Step 2a: per-chunk (2048 counts) reduction -> partial[49]
__global__ __launch_bounds__(256) void scanA_kernel(
    const int* __restrict__ counts, int* __restrict__ partial) {
  __shared__ int lds[256];
  int base = blockIdx.x * SCAN_CHUNK;
  int sum = 0;
  for (int i = threadIdx.x; i < SCAN_CHUNK; i += 256) {
    int idx = base + i;
    sum += (idx < N_NODES) ? counts[idx] : 0;
  }
  lds[threadIdx.x] = sum;
  __syncthreads();
  for (int off = 128; off >= 1; off >>= 1) {
    if (threadIdx.x < off) lds[threadIdx.x] += lds[threadIdx.x + off];
    __syncthreads();
  }
  if (threadIdx.x == 0) partial[blockIdx.x] = lds[0];
}

// Step 2b: single-wave exclusive scan of the 49 partials (in place).
__global__ __launch_bounds__(64) void scanB_kernel(
    int* __restrict__ partial, int* __restrict__ start) {
  int lane = threadIdx.x;
  int orig = (lane < SCAN_NBLK) ? partial[lane] : 0;
  int v = orig;
  for (int off = 1; off < 64; off <<= 1) {
    int t = __shfl_up(v, off);
    if (lane >= off) v += t;
  }
  if (lane < SCAN_NBLK) partial[lane] = v - orig;   // exclusive
  if (lane == 0) start[N_NODES] = N_EDGES;
}

// Step 2c: per-chunk exclusive scan + chunk offset -> start[] and cursor[].
__global__ __launch_bounds__(256) void scanC_kernel(
    const int* __restrict__ counts, const int* __restrict__ blockoff,
    int* __restrict__ start, int* __restrict__ cursor) {
  __shared__ int lds[256];
  const int PT = SCAN_CHUNK / 256;                  // 8
  int base = blockIdx.x * SCAN_CHUNK + threadIdx.x * PT;
  int c[PT];
  int tsum = 0;
#pragma unroll
  for (int k = 0; k < PT; ++k) {
    int idx = base + k;
    c[k] = (idx < N_NODES) ? counts[idx] : 0;
    tsum += c[k];
  }
  lds[threadIdx.x] = tsum;
  __syncthreads();
  for (int off = 1; off < 256; off <<= 1) {         // Hillis-Steele inclusive
    int t = (threadIdx.x >= (unsigned)off) ? lds[threadIdx.x - off] : 0;
    __syncthreads();
    lds[threadIdx.x] += t;
    __syncthreads();
  }
  int run = blockoff[blockIdx.x] + lds[threadIdx.x] - tsum;  // exclusive
#pragma unroll
  for (int k = 0; k < PT; ++k) {
    int idx = base + k;
    if (idx < N_NODES) { start[idx] = run; cursor[idx] = run; }
    run += c[k];
  }
}

// ---------------------------------------------------------------------------
// XCD-affine windowed permute (R10: 130 -> 68 us vs flat permute).
// ---------------------------------------------------------------------------
__global__ __launch_bounds__(256) void permute8_kernel(
    const int* __restrict__ src, const int* __restrict__ dst,
    int* __restrict__ cursor, int* __restrict__ sorted_src) {
  int win  = blockIdx.x & 7;
  int rank = blockIdx.x >> 3;
  int e = rank * 256 + threadIdx.x;
  if (e >= N_EDGES) return;
  int d = dst[e];
  int lo = win * WIN_SZ;
  if (d >= lo && d < lo + WIN_SZ) {
    int pos = atomicAdd(&cursor[d], 1);
    sorted_src[pos] = src[e];
  }
}

// ---------------------------------------------------------------------------
// Gather 1 v3 (dwordx4): lane = (row r = lane>>3, quad q = lane&7).
// One global_load_dwordx4 services 8 rows -> 4x fewer vmem+shfl than R12,
// ~32 rows in flight per wave.  Butterfly shfl_xor(8/16/32) reduces the 8
// row-partials; lanes r==0 write the packed f16 agg row.
// ---------------------------------------------------------------------------
__global__ __launch_bounds__(256) void gather1_kernel(
    const uint4* __restrict__ xq,          // xh as quads [N][8]
    const int* __restrict__ start, const int* __restrict__ ssrc,
    uint4* __restrict__ aggq) {            // aggh as quads [N][8]
  int node = (blockIdx.x * 256 + threadIdx.x) >> 6;
  if (node >= N_NODES) return;
  int lane = threadIdx.x & 63;
  int r = lane >> 3, q = lane & 7;

  float accA[8] = {0.f, 0.f, 0.f, 0.f, 0.f, 0.f, 0.f, 0.f};
  float accB[8] = {0.f, 0.f, 0.f, 0.f, 0.f, 0.f, 0.f, 0.f};

  int s0 = start[node], s1 = start[node + 1];
  for (int base = s0; base < s1; base += 64) {
    int cnt = s1 - base;
    if (cnt > 64) cnt = 64;
    int idxv = (lane < cnt) ? ssrc[base + lane] : 0;
    int j = 0;
    for (; j + 16 <= cnt; j += 16) {
      int iA = clampidx(__shfl(idxv, j + r));
      int iB = clampidx(__shfl(idxv, j + 8 + r));
      quadpk uA, uB;
      uA.v = xq[iA * 8 + q];
      uB.v = xq[iB * 8 + q];
#pragma unroll
      for (int t = 0; t < 8; ++t) {
        accA[t] += (float)uA.h[t];
        accB[t] += (float)uB.h[t];
      }
    }
    for (; j + 8 <= cnt; j += 8) {
      int iA = clampidx(__shfl(idxv, j + r));
      quadpk uA;
      uA.v = xq[iA * 8 + q];
#pragma unroll
      for (int t = 0; t < 8; ++t) accA[t] += (float)uA.h[t];
    }
    if (j < cnt) {
      int nrem = cnt - j;
      int iA = clampidx(__shfl(idxv, j + r));
      if (r < nrem) {
        quadpk uA;
        uA.v = xq[iA * 8 + q];
#pragma unroll
        for (int t = 0; t < 8; ++t) accA[t] += (float)uA.h[t];
      }
    }
  }
#pragma unroll
  for (int t = 0; t < 8; ++t) accA[t] += accB[t];
  // reduce across the 8 row-groups (lanes r differ by strides of 8)
#pragma unroll
  for (int off = 8; off <= 32; off <<= 1) {
#pragma unroll
    for (int t = 0; t < 8; ++t) accA[t] += __shfl_xor(accA[t], off);
  }
  if (r == 0) {
    quadpk o;
#pragma unroll
    for (int t = 0; t < 8; ++t) o.h[t] = (_Float16)accA[t];
    aggq[node * 8 + q] = o.v;
  }
}

// ---------------------------------------------------------------------------
// MLP (MFMA, f16): one wave per 16-node tile.  (unchanged from R8/R12)
// ---------------------------------------------------------------------------
__global__ __launch_bounds__(256) void mlp1_kernel(
    const _Float16* __restrict__ aggh, const _Float16* __restrict__ xh,
    const unsigned* __restrict__ wt1l, const unsigned* __restrict__ wt1r,
    const unsigned* __restrict__ wt2l, const unsigned* __restrict__ wt2r,
    const float* __restrict__ b1, const float* __restrict__ b2,
    _Float16* __restrict__ hlh, float* __restrict__ opart) {
  __shared__ float sH[4][16][68];
  int wid = (blockIdx.x * 256 + threadIdx.x) >> 6;
  int w = (threadIdx.x >> 6) & 3;
  int lane = threadIdx.x & 63;
  int m = lane & 15, quad = lane >> 4;
  if (wid >= N_TILES) return;
  int tile = wid;

  half8 Aa[2], Ax[2];
#pragma unroll
  for (int s = 0; s < 2; ++s) {
    int off = (tile * 16 + m) * 64 + s * 32 + quad * 8;
    Aa[s] = *(const half8*)(aggh + off);
    Ax[s] = *(const half8*)(xh + off);
  }

#pragma unroll
  for (int t = 0; t < 4; ++t) {
    int n = t * 16 + m;
    half8 Bl0 = *(const half8*)(wt1l + n * 32 + quad * 4);
    half8 Bl1 = *(const half8*)(wt1l + n * 32 + 16 + quad * 4);
    half8 Br0 = *(const half8*)(wt1r + n * 32 + quad * 4);
    half8 Br1 = *(const half8*)(wt1r + n * 32 + 16 + quad * 4);
    float4v acc = {0.f, 0.f, 0.f, 0.f};
    acc = __builtin_amdgcn_mfma_f32_16x16x32_f16(Aa[0], Bl0, acc, 0, 0, 0);
    acc = __builtin_amdgcn_mfma_f32_16x16x32_f16(Aa[1], Bl1, acc, 0, 0, 0);
    acc = __builtin_amdgcn_mfma_f32_16x16x32_f16(Ax[0], Br0, acc, 0, 0, 0);
    acc = __builtin_amdgcn_mfma_f32_16x16x32_f16(Ax[1], Br1, acc, 0, 0, 0);
    float bv = b1[n];
#pragma unroll
    for (int rr = 0; rr < 4; ++rr) {
      sH[w][quad * 4 + rr][n] = fmaxf(acc[rr] + bv, 0.f);
    }
  }

  half8 Ah[2];
#pragma unroll
  for (int s = 0; s < 2; ++s) {
    const float* pr = &sH[w][m][s * 32 + quad * 8];
    half8 A;
#pragma unroll
    for (int jj = 0; jj < 8; ++jj) A[jj] = (_Float16)pr[jj];
    Ah[s] = A;
  }

#pragma unroll
  for (int t = 0; t < 3; ++t) {
    int n = t * 16 + m;
    half8 Cl0 = *(const half8*)(wt2l + n * 32 + quad * 4);
    half8 Cl1 = *(const half8*)(wt2l + n * 32 + 16 + quad * 4);
    half8 Cr0 = *(const half8*)(wt2r + n * 32 + quad * 4);
    half8 Cr1 = *(const half8*)(wt2r + n * 32 + 16 + quad * 4);
    float4v acc2 = {0.f, 0.f, 0.f, 0.f};
    float4v acc3 = {0.f, 0.f, 0.f, 0.f};
    acc2 = __builtin_amdgcn_mfma_f32_16x16x32_f16(Ah[0], Cl0, acc2, 0, 0, 0);
    acc2 = __builtin_amdgcn_mfma_f32_16x16x32_f16(Ah[1], Cl1, acc2, 0, 0, 0);
    acc3 = __builtin_amdgcn_mfma_f32_16x16x32_f16(Ah[0], Cr0, acc3, 0, 0, 0);
    acc3 = __builtin_amdgcn_mfma_f32_16x16x32_f16(Ah[1], Cr1, acc3, 0, 0, 0);
    float bv = (n < N_CLASSES) ? b2[n] : 0.f;
#pragma unroll
    for (int rr = 0; rr < 4; ++rr) {
      int row = tile * 16 + quad * 4 + rr;
      hlh[row * NC48 + n] = (_Float16)acc2[rr];
      opart[row * NC48 + n] = acc3[rr] + bv;
    }
  }
}

// ---------------------------------------------------------------------------
// Gather 2 v3 (dwordx4) + softmax: hl rows = 6 quads (96 B).  Lanes with
// q<6 load; butterfly reduce; lanes (r==0, q<6) each own classes q*8..q*8+7.
// ---------------------------------------------------------------------------
__global__ __launch_bounds__(256) void gather2_kernel(
    const uint4* __restrict__ hq,          // hlh as quads [N][6]
    const float4* __restrict__ opart4,     // opart as float4 [N][12]
    const int* __restrict__ start, const int* __restrict__ ssrc,
    float* __restrict__ out) {
  int node = (blockIdx.x * 256 + threadIdx.x) >> 6;
  if (node >= N_NODES) return;
  int lane = threadIdx.x & 63;
  int r = lane >> 3, q = lane & 7;
  bool qOK = (q < 6);

  // own opart features (issued early)
  float op[8] = {0.f, 0.f, 0.f, 0.f, 0.f, 0.f, 0.f, 0.f};
  if (r == 0 && qOK) {
    float4 a = opart4[node * 12 + q * 2];
    float4 b = opart4[node * 12 + q * 2 + 1];
    op[0] = a.x; op[1] = a.y; op[2] = a.z; op[3] = a.w;
    op[4] = b.x; op[5] = b.y; op[6] = b.z; op[7] = b.w;
  }

  float accA[8] = {0.f, 0.f, 0.f, 0.f, 0.f, 0.f, 0.f, 0.f};
  float accB[8] = {0.f, 0.f, 0.f, 0.f, 0.f, 0.f, 0.f, 0.f};

  int s0 = start[node], s1 = start[node + 1];
  for (int base = s0; base < s1; base += 64) {
    int cnt = s1 - base;
    if (cnt > 64) cnt = 64;
    int idxv = (lane < cnt) ? ssrc[base + lane] : 0;
    int j = 0;
    for (; j + 16 <= cnt; j += 16) {
      int iA = clampidx(__shfl(idxv, j + r));
      int iB = clampidx(__shfl(idxv, j + 8 + r));
      if (qOK) {
        quadpk uA, uB;
        uA.v = hq[iA * 6 + q];
        uB.v = hq[iB * 6 + q];
#pragma unroll
        for (int t = 0; t < 8; ++t) {
          accA[t] += (float)uA.h[t];
          accB[t] += (float)uB.h[t];
        }
      }
    }
    for (; j + 8 <= cnt; j += 8) {
      int iA = clampidx(__shfl(idxv, j + r));
      if (qOK) {
        quadpk uA;
        uA.v = hq[iA * 6 + q];
#pragma unroll
        for (int t = 0; t < 8; ++t) accA[t] += (float)uA.h[t];
      }
    }
    if (j < cnt) {
      int nrem = cnt - j;
      int iA = clampidx(__shfl(idxv, j + r));
      if (r < nrem && qOK) {
        quadpk uA;
        uA.v = hq[iA * 6 + q];
#pragma unroll
        for (int t = 0; t < 8; ++t) accA[t] += (float)uA.h[t];
      }
    }
  }
#pragma unroll
  for (int t = 0; t < 8; ++t) accA[t] += accB[t];
#pragma unroll
  for (int off = 8; off <= 32; off <<= 1) {
#pragma unroll
    for (int t = 0; t < 8; ++t) accA[t] += __shfl_xor(accA[t], off);
  }

  // lanes (r==0, q<6): o[t] = opart + agg for class f = q*8+t (valid f<41)
  bool own = (r == 0) && qOK;
  float o[8];
  float lmax = -INFINITY;
#pragma unroll
  for (int t = 0; t < 8; ++t) {
    int f = q * 8 + t;
    o[t] = op[t] + accA[t];
    if (own && f < N_CLASSES) lmax = fmaxf(lmax, o[t]);
  }
  float vm = own ? lmax : -INFINITY;
#pragma unroll
  for (int off = 32; off >= 1; off >>= 1) vm = fmaxf(vm, __shfl_xor(vm, off));
  float lsum = 0.f;
#pragma unroll
  for (int t = 0; t < 8; ++t) {
    int f = q * 8 + t;
    if (own && f < N_CLASSES) lsum += expf(o[t] - vm);
  }
#pragma unroll
  for (int off = 32; off >= 1; off >>= 1) lsum += __shfl_xor(lsum, off);
  float lse = logf(lsum);
  if (own) {
#pragma unroll
    for (int t = 0; t < 8; ++t) {
      int f = q * 8 + t;
      if (f < N_CLASSES) out[node * N_CLASSES + f] = o[t] - vm - lse;
    }
  }
}

// ---------------------------------------------------------------------------
extern "C" void kernel_launch(void* const* d_in, const int* in_sizes, int n_in,
                              void* d_out, int out_size, void* d_ws, size_t ws_size,
                              hipStream_t stream) {
  const float* x   = (const float*)d_in[0];
  const float* W1l = (const float*)d_in[1];
  const float* W1r = (const float*)d_in[2];
  const float* b1  = (const float*)d_in[3];
  const float* W2l = (const float*)d_in[4];
  const float* W2r = (const float*)d_in[5];
  const float* b2  = (const float*)d_in[6];
  const int*   src = (const int*)d_in[7];
  const int*   dst = (const int*)d_in[8];
  float* out = (float*)d_out;

  int* counts  = (int*)d_ws;
  int* start   = counts + N_NODES;
  int* cursor  = start + (N_NODES + 1);
  int* partial = cursor + N_NODES;
  int* ssrc    = partial + 64;
  unsigned* wt1l = (unsigned*)(ssrc + N_EDGES);
  unsigned* wt1r = wt1l + 2048;
  unsigned* wt2l = wt1r + 2048;
  unsigned* wt2r = wt2l + 1536;
  // 256-B align opart so all downstream quad accesses are naturally aligned
  uintptr_t pal = ((uintptr_t)(wt2r + 1536) + 255) & ~(uintptr_t)255;
  float* opart   = (float*)pal;
  _Float16* xh   = (_Float16*)(opart + (size_t)N_NODES * NC48);
  _Float16* aggh = xh + (size_t)N_NODES * 64;
  _Float16* hlh  = aggh + (size_t)N_NODES * 64;

  int eblocks = (N_EDGES + 255) / 256;   // 6250

  zeroc_kernel<<<(N_NODES + 255) / 256, 256, 0, stream>>>(counts);
  packx_kernel<<<(N_NODES * 64 + 255) / 256, 256, 0, stream>>>(x, xh);
  packwts_kernel<<<(7168 + 255) / 256, 256, 0, stream>>>(
      W1l, W1r, W2l, W2r, wt1l, wt1r, wt2l, wt2r);
  hist_kernel<<<eblocks, 256, 0, stream>>>(dst, counts);
  scanA_kernel<<<SCAN_NBLK, 256, 0, stream>>>(counts, partial);
  scanB_kernel<<<1, 64, 0, stream>>>(partial, start);
  scanC_kernel<<<SCAN_NBLK, 256, 0, stream>>>(counts, partial, start, cursor);
  permute8_kernel<<<eblocks * N_WIN, 256, 0, stream>>>(src, dst, cursor, ssrc);

  int gblocks = (N_NODES * 64 + 255) / 256;   // one wave per node
  gather1_kernel<<<gblocks, 256, 0, stream>>>(
      (const uint4*)xh, start, ssrc, (uint4*)aggh);
  mlp1_kernel<<<(N_TILES * 64 + 255) / 256, 256, 0, stream>>>(
      aggh, xh, wt1l, wt1r, wt2l, wt2r, b1, b2, hlh, opart);
  gather2_kernel<<<gblocks, 256, 0, stream>>>(
      (const uint4*)hlh, (const float4*)opart, start, ssrc, out);
}

// Round 14
// 349.862 us; speedup vs baseline: 2.1128x; 1.0485x over previous
//
#include <hip/hip_runtime.h>
#include <hip/hip_bf16.h>
#include <math.h>

#define N_NODES   100000
#define N_EDGES   1600000
#define IN_FEAT   50
#define HIDDEN    64
#define N_CLASSES 41
#define NC48      48          // padded class width
#define N_TILES   (N_NODES / 16)   // 6250 exactly

#define N_WIN     8
#define WIN_SZ    ((N_NODES + N_WIN - 1) / N_WIN)   // 12500

#define SCAN_CHUNK 2048
#define SCAN_NBLK  ((N_NODES + SCAN_CHUNK - 1) / SCAN_CHUNK)   // 49 (<=64)

typedef __attribute__((ext_vector_type(8))) _Float16 half8;
typedef __attribute__((ext_vector_type(4))) float   float4v;

union f16pk { _Float16 h[2]; unsigned u; };
union quadpk { uint4 v; _Float16 h[8]; };

// index clamp: any value outside [0,N_NODES) becomes 0 (defensive; see R11)
__device__ __forceinline__ int clampidx(int i) {
  return ((unsigned)i < (unsigned)N_NODES) ? i : 0;
}

// ---------------------------------------------------------------------------
// Zero the per-node counters.
// ---------------------------------------------------------------------------
__global__ __launch_bounds__(256) void zeroc_kernel(int* __restrict__ counts) {
  int i = blockIdx.x * 256 + threadIdx.x;
  if (i < N_NODES) counts[i] = 0;
}

// ---------------------------------------------------------------------------
// Prep A: x (f32 [N][50]) -> xh (f16 [N][64], k-padded with zeros)
// ---------------------------------------------------------------------------
__global__ __launch_bounds__(256) void packx_kernel(
    const float* __restrict__ x, _Float16* __restrict__ xh) {
  int i = blockIdx.x * 256 + threadIdx.x;
  if (i >= N_NODES * 64) return;
  int node = i >> 6, c = i & 63;
  xh[i] = (c < IN_FEAT) ? (_Float16)x[node * IN_FEAT + c] : (_Float16)0.f;
}

// ---------------------------------------------------------------------------
// Prep B: pack transposed f16-pair weights for MFMA B-fragments.
// ---------------------------------------------------------------------------
__global__ __launch_bounds__(256) void packwts_kernel(
    const float* __restrict__ W1l, const float* __restrict__ W1r,
    const float* __restrict__ W2l, const float* __restrict__ W2r,
    unsigned* __restrict__ wt1l, unsigned* __restrict__ wt1r,
    unsigned* __restrict__ wt2l, unsigned* __restrict__ wt2r) {
  int i = blockIdx.x * 256 + threadIdx.x;
  f16pk pk;
  if (i < 2048 * 2) {                       // layer-1 weights
    int which = i >> 11, j = i & 2047;
    int n = j >> 5, kp = j & 31;
    const float* W = which ? W1r : W1l;
    int k0 = 2 * kp, k1 = 2 * kp + 1;
    pk.h[0] = (_Float16)((k0 < IN_FEAT) ? W[k0 * HIDDEN + n] : 0.f);
    pk.h[1] = (_Float16)((k1 < IN_FEAT) ? W[k1 * HIDDEN + n] : 0.f);
    (which ? wt1r : wt1l)[j] = pk.u;
  } else if (i < 4096 + 2 * 1536) {         // layer-2 weights
    int j = i - 4096;
    int which = (j >= 1536), jj = which ? j - 1536 : j;
    int n = jj >> 5, kp = jj & 31;
    const float* W = which ? W2r : W2l;
    pk.h[0] = (_Float16)((n < N_CLASSES) ? W[(2 * kp) * N_CLASSES + n] : 0.f);
    pk.h[1] = (_Float16)((n < N_CLASSES) ? W[(2 * kp + 1) * N_CLASSES + n] : 0.f);
    (which ? wt2r : wt2l)[jj] = pk.u;
  }
}

// ---------------------------------------------------------------------------
// Counting-sort by dst.  Step 1: histogram of dst.
// ---------------------------------------------------------------------------
__global__ __launch_bounds__(256) void hist_kernel(
    const int* __restrict__ dst, int* __restrict__ counts) {
  int e = blockIdx.x * 256 + threadIdx.x;
  if (e < N_EDGES) atomicAdd(&counts[dst[e]], 1);
}

// Step 2a: per-chunk (2048 counts) reduction -> partial[49]
__global__ __launch_bounds__(256) void scanA_kernel(
    const int* __restrict__ counts, int* __restrict__ partial) {
  __shared__ int lds[256];
  int base = blockIdx.x * SCAN_CHUNK;
  int sum = 0;
  for (int i = threadIdx.x; i < SCAN_CHUNK; i += 256) {
    int idx = base + i;
    sum += (idx < N_NODES) ? counts[idx] : 0;
  }
  lds[threadIdx.x] = sum;
  __syncthreads();
  for (int off = 128; off >= 1; off >>= 1) {
    if (threadIdx.x < off) lds[threadIdx.x] += lds[threadIdx.x + off];
    __syncthreads();
  }
  if (threadIdx.x == 0) partial[blockIdx.x] = lds[0];
}

// Step 2b: single-wave exclusive scan of the 49 partials (in place).
__global__ __launch_bounds__(64) void scanB_kernel(
    int* __restrict__ partial, int* __restrict__ start) {
  int lane = threadIdx.x;
  int orig = (lane < SCAN_NBLK) ? partial[lane] : 0;
  int v = orig;
  for (int off = 1; off < 64; off <<= 1) {
    int t = __shfl_up(v, off);
    if (lane >= off) v += t;
  }
  if (lane < SCAN_NBLK) partial[lane] = v - orig;   // exclusive
  if (lane == 0) start[N_NODES] = N_EDGES;
}

// Step 2c: per-chunk exclusive scan + chunk offset -> start[] and cursor[].
__global__ __launch_bounds__(256) void scanC_kernel(
    const int* __restrict__ counts, const int* __restrict__ blockoff,
    int* __restrict__ start, int* __restrict__ cursor) {
  __shared__ int lds[256];
  const int PT = SCAN_CHUNK / 256;                  // 8
  int base = blockIdx.x * SCAN_CHUNK + threadIdx.x * PT;
  int c[PT];
  int tsum = 0;
#pragma unroll
  for (int k = 0; k < PT; ++k) {
    int idx = base + k;
    c[k] = (idx < N_NODES) ? counts[idx] : 0;
    tsum += c[k];
  }
  lds[threadIdx.x] = tsum;
  __syncthreads();
  for (int off = 1; off < 256; off <<= 1) {         // Hillis-Steele inclusive
    int t = (threadIdx.x >= (unsigned)off) ? lds[threadIdx.x - off] : 0;
    __syncthreads();
    lds[threadIdx.x] += t;
    __syncthreads();
  }
  int run = blockoff[blockIdx.x] + lds[threadIdx.x] - tsum;  // exclusive
#pragma unroll
  for (int k = 0; k < PT; ++k) {
    int idx = base + k;
    if (idx < N_NODES) { start[idx] = run; cursor[idx] = run; }
    run += c[k];
  }
}

// ---------------------------------------------------------------------------
// XCD-affine windowed permute (R10: 130 -> 68 us vs flat permute).
// ---------------------------------------------------------------------------
__global__ __launch_bounds__(256) void permute8_kernel(
    const int* __restrict__ src, const int* __restrict__ dst,
    int* __restrict__ cursor, int* __restrict__ sorted_src) {
  int win  = blockIdx.x & 7;
  int rank = blockIdx.x >> 3;
  int e = rank * 256 + threadIdx.x;
  if (e >= N_EDGES) return;
  int d = dst[e];
  int lo = win * WIN_SZ;
  if (d >= lo && d < lo + WIN_SZ) {
    int pos = atomicAdd(&cursor[d], 1);
    sorted_src[pos] = src[e];
  }
}

// ---------------------------------------------------------------------------
// Fused gather1 + MLP: one block per 16-node tile (6250 blocks).
// Waves 0-3 each gather 4 nodes (R13 dwordx4 pattern) -> agg rows in f32 LDS
// (no aggh global round-trip, no intermediate f16 quantization).
// Barrier; wave 0 runs the MFMA MLP for the tile:
//   h  = relu(agg@W1l + x@W1r + b1)   (LDS only)
//   hl = h@W2l            -> hlh   [N][48] f16
//   op = h@W2r + b2       -> opart [N][48] f32
// ---------------------------------------------------------------------------
__global__ __launch_bounds__(256) void g1mlp_kernel(
    const uint4* __restrict__ xq,          // xh as quads [N][8]
    const int* __restrict__ start, const int* __restrict__ ssrc,
    const _Float16* __restrict__ xh,
    const unsigned* __restrict__ wt1l, const unsigned* __restrict__ wt1r,
    const unsigned* __restrict__ wt2l, const unsigned* __restrict__ wt2r,
    const float* __restrict__ b1, const float* __restrict__ b2,
    _Float16* __restrict__ hlh, float* __restrict__ opart) {
  __shared__ float aggF[16][64];    // 4 KB: f32 agg rows for the tile
  __shared__ float sH[16][68];      // 4.25 KB: h round-trip (padded)
  int tile = blockIdx.x;
  int wv = threadIdx.x >> 6;        // wave 0..3
  int lane = threadIdx.x & 63;
  int r = lane >> 3, q = lane & 7;

  // ---- gather phase: wave wv handles nodes tile*16 + wv*4 .. +4 ----
  for (int k = 0; k < 4; ++k) {
    int node = tile * 16 + wv * 4 + k;

    float accA[8] = {0.f, 0.f, 0.f, 0.f, 0.f, 0.f, 0.f, 0.f};
    float accB[8] = {0.f, 0.f, 0.f, 0.f, 0.f, 0.f, 0.f, 0.f};

    int s0 = start[node], s1 = start[node + 1];
    for (int base = s0; base < s1; base += 64) {
      int cnt = s1 - base;
      if (cnt > 64) cnt = 64;
      int idxv = (lane < cnt) ? ssrc[base + lane] : 0;
      int j = 0;
      for (; j + 16 <= cnt; j += 16) {
        int iA = clampidx(__shfl(idxv, j + r));
        int iB = clampidx(__shfl(idxv, j + 8 + r));
        quadpk uA, uB;
        uA.v = xq[iA * 8 + q];
        uB.v = xq[iB * 8 + q];
#pragma unroll
        for (int t = 0; t < 8; ++t) {
          accA[t] += (float)uA.h[t];
          accB[t] += (float)uB.h[t];
        }
      }
      for (; j + 8 <= cnt; j += 8) {
        int iA = clampidx(__shfl(idxv, j + r));
        quadpk uA;
        uA.v = xq[iA * 8 + q];
#pragma unroll
        for (int t = 0; t < 8; ++t) accA[t] += (float)uA.h[t];
      }
      if (j < cnt) {
        int nrem = cnt - j;
        int iA = clampidx(__shfl(idxv, j + r));
        if (r < nrem) {
          quadpk uA;
          uA.v = xq[iA * 8 + q];
#pragma unroll
          for (int t = 0; t < 8; ++t) accA[t] += (float)uA.h[t];
        }
      }
    }
#pragma unroll
    for (int t = 0; t < 8; ++t) accA[t] += accB[t];
#pragma unroll
    for (int off = 8; off <= 32; off <<= 1) {
#pragma unroll
      for (int t = 0; t < 8; ++t) accA[t] += __shfl_xor(accA[t], off);
    }
    if (r == 0) {
      int nl = wv * 4 + k;
#pragma unroll
      for (int t = 0; t < 8; ++t) aggF[nl][q * 8 + t] = accA[t];
    }
  }
  __syncthreads();

  // ---- MLP phase: wave 0 only ----
  if (wv != 0) return;
  int m = lane & 15, quad = lane >> 4;

  half8 Aa[2], Ax[2];
#pragma unroll
  for (int s = 0; s < 2; ++s) {
    const float* pa = &aggF[m][s * 32 + quad * 8];
    half8 A;
#pragma unroll
    for (int jj = 0; jj < 8; ++jj) A[jj] = (_Float16)pa[jj];
    Aa[s] = A;
    Ax[s] = *(const half8*)(xh + (tile * 16 + m) * 64 + s * 32 + quad * 8);
  }

#pragma unroll
  for (int t = 0; t < 4; ++t) {
    int n = t * 16 + m;
    half8 Bl0 = *(const half8*)(wt1l + n * 32 + quad * 4);
    half8 Bl1 = *(const half8*)(wt1l + n * 32 + 16 + quad * 4);
    half8 Br0 = *(const half8*)(wt1r + n * 32 + quad * 4);
    half8 Br1 = *(const half8*)(wt1r + n * 32 + 16 + quad * 4);
    float4v acc = {0.f, 0.f, 0.f, 0.f};
    acc = __builtin_amdgcn_mfma_f32_16x16x32_f16(Aa[0], Bl0, acc, 0, 0, 0);
    acc = __builtin_amdgcn_mfma_f32_16x16x32_f16(Aa[1], Bl1, acc, 0, 0, 0);
    acc = __builtin_amdgcn_mfma_f32_16x16x32_f16(Ax[0], Br0, acc, 0, 0, 0);
    acc = __builtin_amdgcn_mfma_f32_16x16x32_f16(Ax[1], Br1, acc, 0, 0, 0);
    float bv = b1[n];
#pragma unroll
    for (int rr = 0; rr < 4; ++rr) {
      sH[quad * 4 + rr][n] = fmaxf(acc[rr] + bv, 0.f);
    }
  }

  half8 Ah[2];
#pragma unroll
  for (int s = 0; s < 2; ++s) {
    const float* pr = &sH[m][s * 32 + quad * 8];
    half8 A;
#pragma unroll
    for (int jj = 0; jj < 8; ++jj) A[jj] = (_Float16)pr[jj];
    Ah[s] = A;
  }

#pragma unroll
  for (int t = 0; t < 3; ++t) {
    int n = t * 16 + m;
    half8 Cl0 = *(const half8*)(wt2l + n * 32 + quad * 4);
    half8 Cl1 = *(const half8*)(wt2l + n * 32 + 16 + quad * 4);
    half8 Cr0 = *(const half8*)(wt2r + n * 32 + quad * 4);
    half8 Cr1 = *(const half8*)(wt2r + n * 32 + 16 + quad * 4);
    float4v acc2 = {0.f, 0.f, 0.f, 0.f};
    float4v acc3 = {0.f, 0.f, 0.f, 0.f};
    acc2 = __builtin_amdgcn_mfma_f32_16x16x32_f16(Ah[0], Cl0, acc2, 0, 0, 0);
    acc2 = __builtin_amdgcn_mfma_f32_16x16x32_f16(Ah[1], Cl1, acc2, 0, 0, 0);
    acc3 = __builtin_amdgcn_mfma_f32_16x16x32_f16(Ah[0], Cr0, acc3, 0, 0, 0);
    acc3 = __builtin_amdgcn_mfma_f32_16x16x32_f16(Ah[1], Cr1, acc3, 0, 0, 0);
    float bv = (n < N_CLASSES) ? b2[n] : 0.f;
#pragma unroll
    for (int rr = 0; rr < 4; ++rr) {
      int row = tile * 16 + quad * 4 + rr;
      hlh[row * NC48 + n] = (_Float16)acc2[rr];
      opart[row * NC48 + n] = acc3[rr] + bv;
    }
  }
}

// ---------------------------------------------------------------------------
// Gather 2 v3 (dwordx4) + softmax: hl rows = 6 quads (96 B).  Lanes with
// q<6 load; butterfly reduce; lanes (r==0, q<6) each own classes q*8..q*8+7.
// ---------------------------------------------------------------------------
__global__ __launch_bounds__(256) void gather2_kernel(
    const uint4* __restrict__ hq,          // hlh as quads [N][6]
    const float4* __restrict__ opart4,     // opart as float4 [N][12]
    const int* __restrict__ start, const int* __restrict__ ssrc,
    float* __restrict__ out) {
  int node = (blockIdx.x * 256 + threadIdx.x) >> 6;
  if (node >= N_NODES) return;
  int lane = threadIdx.x & 63;
  int r = lane >> 3, q = lane & 7;
  bool qOK = (q < 6);

  // own opart features (issued early)
  float op[8] = {0.f, 0.f, 0.f, 0.f, 0.f, 0.f, 0.f, 0.f};
  if (r == 0 && qOK) {
    float4 a = opart4[node * 12 + q * 2];
    float4 b = opart4[node * 12 + q * 2 + 1];
    op[0] = a.x; op[1] = a.y; op[2] = a.z; op[3] = a.w;
    op[4] = b.x; op[5] = b.y; op[6] = b.z; op[7] = b.w;
  }

  float accA[8] = {0.f, 0.f, 0.f, 0.f, 0.f, 0.f, 0.f, 0.f};
  float accB[8] = {0.f, 0.f, 0.f, 0.f, 0.f, 0.f, 0.f, 0.f};

  int s0 = start[node], s1 = start[node + 1];
  for (int base = s0; base < s1; base += 64) {
    int cnt = s1 - base;
    if (cnt > 64) cnt = 64;
    int idxv = (lane < cnt) ? ssrc[base + lane] : 0;
    int j = 0;
    for (; j + 16 <= cnt; j += 16) {
      int iA = clampidx(__shfl(idxv, j + r));
      int iB = clampidx(__shfl(idxv, j + 8 + r));
      if (qOK) {
        quadpk uA, uB;
        uA.v = hq[iA * 6 + q];
        uB.v = hq[iB * 6 + q];
#pragma unroll
        for (int t = 0; t < 8; ++t) {
          accA[t] += (float)uA.h[t];
          accB[t] += (float)uB.h[t];
        }
      }
    }
    for (; j + 8 <= cnt; j += 8) {
      int iA = clampidx(__shfl(idxv, j + r));
      if (qOK) {
        quadpk uA;
        uA.v = hq[iA * 6 + q];
#pragma unroll
        for (int t = 0; t < 8; ++t) accA[t] += (float)uA.h[t];
      }
    }
    if (j < cnt) {
      int nrem = cnt - j;
      int iA = clampidx(__shfl(idxv, j + r));
      if (r < nrem && qOK) {
        quadpk uA;
        uA.v = hq[iA * 6 + q];
#pragma unroll
        for (int t = 0; t < 8; ++t) accA[t] += (float)uA.h[t];
      }
    }
  }
#pragma unroll
  for (int t = 0; t < 8; ++t) accA[t] += accB[t];
#pragma unroll
  for (int off = 8; off <= 32; off <<= 1) {
#pragma unroll
    for (int t = 0; t < 8; ++t) accA[t] += __shfl_xor(accA[t], off);
  }

  // lanes (r==0, q<6): o[t] = opart + agg for class f = q*8+t (valid f<41)
  bool own = (r == 0) && qOK;
  float o[8];
  float lmax = -INFINITY;
#pragma unroll
  for (int t = 0; t < 8; ++t) {
    int f = q * 8 + t;
    o[t] = op[t] + accA[t];
    if (own && f < N_CLASSES) lmax = fmaxf(lmax, o[t]);
  }
  float vm = own ? lmax : -INFINITY;
#pragma unroll
  for (int off = 32; off >= 1; off >>= 1) vm = fmaxf(vm, __shfl_xor(vm, off));
  float lsum = 0.f;
#pragma unroll
  for (int t = 0; t < 8; ++t) {
    int f = q * 8 + t;
    if (own && f < N_CLASSES) lsum += expf(o[t] - vm);
  }
#pragma unroll
  for (int off = 32; off >= 1; off >>= 1) lsum += __shfl_xor(lsum, off);
  float lse = logf(lsum);
  if (own) {
#pragma unroll
    for (int t = 0; t < 8; ++t) {
      int f = q * 8 + t;
      if (f < N_CLASSES) out[node * N_CLASSES + f] = o[t] - vm - lse;
    }
  }
}

// ---------------------------------------------------------------------------
extern "C" void kernel_launch(void* const* d_in, const int* in_sizes, int n_in,
                              void* d_out, int out_size, void* d_ws, size_t ws_size,
                              hipStream_t stream) {
  const float* x   = (const float*)d_in[0];
  const float* W1l = (const float*)d_in[1];
  const float* W1r = (const float*)d_in[2];
  const float* b1  = (const float*)d_in[3];
  const float* W2l = (const float*)d_in[4];
  const float* W2r = (const float*)d_in[5];
  const float* b2  = (const float*)d_in[6];
  const int*   src = (const int*)d_in[7];
  const int*   dst = (const int*)d_in[8];
  float* out = (float*)d_out;

  int* counts  = (int*)d_ws;
  int* start   = counts + N_NODES;
  int* cursor  = start + (N_NODES + 1);
  int* partial = cursor + N_NODES;
  int* ssrc    = partial + 64;
  unsigned* wt1l = (unsigned*)(ssrc + N_EDGES);
  unsigned* wt1r = wt1l + 2048;
  unsigned* wt2l = wt1r + 2048;
  unsigned* wt2r = wt2l + 1536;
  // 256-B align opart so all downstream quad accesses are naturally aligned
  uintptr_t pal = ((uintptr_t)(wt2r + 1536) + 255) & ~(uintptr_t)255;
  float* opart   = (float*)pal;
  _Float16* xh   = (_Float16*)(opart + (size_t)N_NODES * NC48);
  _Float16* hlh  = xh + (size_t)N_NODES * 64;

  int eblocks = (N_EDGES + 255) / 256;   // 6250

  zeroc_kernel<<<(N_NODES + 255) / 256, 256, 0, stream>>>(counts);
  packx_kernel<<<(N_NODES * 64 + 255) / 256, 256, 0, stream>>>(x, xh);
  packwts_kernel<<<(7168 + 255) / 256, 256, 0, stream>>>(
      W1l, W1r, W2l, W2r, wt1l, wt1r, wt2l, wt2r);
  hist_kernel<<<eblocks, 256, 0, stream>>>(dst, counts);
  scanA_kernel<<<SCAN_NBLK, 256, 0, stream>>>(counts, partial);
  scanB_kernel<<<1, 64, 0, stream>>>(partial, start);
  scanC_kernel<<<SCAN_NBLK, 256, 0, stream>>>(counts, partial, start, cursor);
  permute8_kernel<<<eblocks * N_WIN, 256, 0, stream>>>(src, dst, cursor, ssrc);

  g1mlp_kernel<<<N_TILES, 256, 0, stream>>>(
      (const uint4*)xh, start, ssrc, xh, wt1l, wt1r, wt2l, wt2r,
      b1, b2, hlh, opart);

  int gblocks = (N_NODES * 64 + 255) / 256;   // one wave per node
  gather2_kernel<<<gblocks, 256, 0, stream>>>(
      (const uint4*)hlh, (const float4*)opart, start, ssrc, out);
}